// Round 8
// baseline (273.298 us; speedup 1.0000x reference)
//
#include <hip/hip_runtime.h>
#include <hip/hip_bf16.h>
#include <cstdint>
#include <type_traits>

using bf16_t = __hip_bfloat16;
typedef __bf16 bf16x8 __attribute__((ext_vector_type(8)));
typedef float f32x4 __attribute__((ext_vector_type(4)));

typedef __attribute__((address_space(3))) uint32_t lds_u32_t;
typedef const __attribute__((address_space(1))) uint32_t glb_u32_t;

// ---------------- f32 -> bf16 convert, 8 elems/thread ----------------
__global__ void cvt_f32_to_bf16(const float* __restrict__ in, bf16_t* __restrict__ out, int n8) {
  int stride = gridDim.x * blockDim.x;
  for (int i = blockIdx.x * blockDim.x + threadIdx.x; i < n8; i += stride) {
    const float4* p = reinterpret_cast<const float4*>(in) + (size_t)i * 2;
    float4 a = p[0];
    float4 b = p[1];
    bf16_t o[8];
    o[0] = __float2bfloat16(a.x); o[1] = __float2bfloat16(a.y);
    o[2] = __float2bfloat16(a.z); o[3] = __float2bfloat16(a.w);
    o[4] = __float2bfloat16(b.x); o[5] = __float2bfloat16(b.y);
    o[6] = __float2bfloat16(b.z); o[7] = __float2bfloat16(b.w);
    *reinterpret_cast<uint4*>(out + (size_t)i * 8) = *reinterpret_cast<const uint4*>(o);
  }
}

// ---------------- bf16 GEMM: C[M,N] = A[M,K] * Bt[N,K]^T ----------------
// 128x128 tile, BK=32, 4 waves (2x2 of 64x64), mfma_f32_16x16x32_bf16.
// Staging via global_load_lds width=16 (m97 pattern), 2-barrier K-loop.
template <typename OutT>
__global__ __launch_bounds__(256) void gemm_bt(const bf16_t* __restrict__ A,
                                               const bf16_t* __restrict__ Bt,
                                               OutT* __restrict__ C,
                                               int M, int N, int K) {
  __shared__ __align__(16) bf16_t As[128 * 32];
  __shared__ __align__(16) bf16_t Bs[128 * 32];
  const int tid = threadIdx.x;
  const int lane = tid & 63;
  const int w = tid >> 6;
  const int wm = w >> 1, wn = w & 1;
  const int lr = lane & 15, lc = lane >> 4;
  const int m0 = blockIdx.y * 128, n0 = blockIdx.x * 128;

  const int c0 = tid, c1 = tid + 256;
  const bf16_t* a0p = A + (size_t)(m0 + (c0 >> 2)) * K + (c0 & 3) * 8;
  const bf16_t* a1p = A + (size_t)(m0 + (c1 >> 2)) * K + (c1 & 3) * 8;
  const bf16_t* b0p = Bt + (size_t)(n0 + (c0 >> 2)) * K + (c0 & 3) * 8;
  const bf16_t* b1p = Bt + (size_t)(n0 + (c1 >> 2)) * K + (c1 & 3) * 8;

  bf16_t* asb0 = As + w * 512;
  bf16_t* asb1 = As + 2048 + w * 512;
  bf16_t* bsb0 = Bs + w * 512;
  bf16_t* bsb1 = Bs + 2048 + w * 512;

  f32x4 acc[4][4] = {};

  for (int k0 = 0; k0 < K; k0 += 32) {
    __syncthreads();
    __builtin_amdgcn_global_load_lds((glb_u32_t*)(a0p + k0), (lds_u32_t*)asb0, 16, 0, 0);
    __builtin_amdgcn_global_load_lds((glb_u32_t*)(a1p + k0), (lds_u32_t*)asb1, 16, 0, 0);
    __builtin_amdgcn_global_load_lds((glb_u32_t*)(b0p + k0), (lds_u32_t*)bsb0, 16, 0, 0);
    __builtin_amdgcn_global_load_lds((glb_u32_t*)(b1p + k0), (lds_u32_t*)bsb1, 16, 0, 0);
    __syncthreads();

    bf16x8 af[4], bfv[4];
#pragma unroll
    for (int i = 0; i < 4; ++i)
      af[i] = *reinterpret_cast<const bf16x8*>(&As[(wm * 64 + i * 16 + lr) * 32 + lc * 8]);
#pragma unroll
    for (int i = 0; i < 4; ++i)
      bfv[i] = *reinterpret_cast<const bf16x8*>(&Bs[(wn * 64 + i * 16 + lr) * 32 + lc * 8]);
#pragma unroll
    for (int i = 0; i < 4; ++i)
#pragma unroll
      for (int j = 0; j < 4; ++j)
        acc[i][j] = __builtin_amdgcn_mfma_f32_16x16x32_bf16(af[i], bfv[j], acc[i][j], 0, 0, 0);
  }

#pragma unroll
  for (int i = 0; i < 4; ++i)
#pragma unroll
    for (int j = 0; j < 4; ++j) {
      int row = m0 + wm * 64 + i * 16 + lc * 4;
      int col = n0 + wn * 64 + j * 16 + lr;
#pragma unroll
      for (int r = 0; r < 4; ++r) {
        float v = acc[i][j][r];
        if constexpr (std::is_same<OutT, float>::value)
          C[(size_t)(row + r) * N + col] = v;
        else
          C[(size_t)(row + r) * N + col] = __float2bfloat16(v);
      }
    }
}

// ---------------- RoPE + scatter qkv -> Q (scaled), K, V ----------------
__global__ __launch_bounds__(256) void rope_scatter(const bf16_t* __restrict__ qkv,
                                                    const float* __restrict__ cosp,
                                                    const float* __restrict__ sinp,
                                                    bf16_t* __restrict__ Q,
                                                    bf16_t* __restrict__ K,
                                                    bf16_t* __restrict__ V) {
  const int row = blockIdx.x;  // b*2048 + t
  const int b = row >> 11, t = row & 2047;
  const bf16_t* src = qkv + (size_t)row * 3072;
  for (int n = threadIdx.x; n < 3072; n += 256) {
    int g = n / 768;
    int r = n - g * 768;
    int slot = r >> 7;
    int d = r & 127;
    if (slot == 5) {
      V[(((size_t)(b * 4 + g)) * 2048 + t) * 128 + d] = src[n];
    } else {
      float v = __bfloat162float(src[n]);
      float other = __bfloat162float(src[n ^ 64]);
      float c = cosp[t * 128 + d];
      float s = sinp[t * 128 + d];
      float rot = (d < 64) ? -other : other;
      float res = v * c + rot * s;
      if (slot < 4) {
        int h = g * 4 + slot;
        // fold softmax scale 1/sqrt(128) AND log2(e) into Q (attn uses exp2)
        Q[(((size_t)(b * 16 + h)) * 2048 + t) * 128 + d] =
            __float2bfloat16(res * (0.08838834764831843f * 1.4426950408889634f));
      } else {
        K[(((size_t)(b * 4 + g)) * 2048 + t) * 128 + d] = __float2bfloat16(res);
      }
    }
  }
}

// ---------------- V [bg][t][d] -> Vt [bg][d][t] ----------------
__global__ void transpose_v(const bf16_t* __restrict__ V, bf16_t* __restrict__ Vt) {
  __shared__ bf16_t tile[32][33];
  const int bg = blockIdx.z;
  const int t0 = blockIdx.x * 32;
  const int d0 = blockIdx.y * 32;
  const bf16_t* src = V + (size_t)bg * 2048 * 128;
  bf16_t* dst = Vt + (size_t)bg * 128 * 2048;
#pragma unroll
  for (int i = threadIdx.y; i < 32; i += 8)
    tile[i][threadIdx.x] = src[(size_t)(t0 + i) * 128 + d0 + threadIdx.x];
  __syncthreads();
#pragma unroll
  for (int i = threadIdx.y; i < 32; i += 8)
    dst[(size_t)(d0 + i) * 2048 + t0 + threadIdx.x] = tile[threadIdx.x][i];
}

// ---------------- sliding-window flash attention (v8) --------------------
// Round-7 math + equalized blocks, but the 2-phase drain-every-tile barrier
// is replaced with a 3-deep counted-vmcnt pipeline (T3+T4):
//   iter t: issue stage(t+2) [4 vm ops] -> vmcnt(4) (waits t+1, a full iter
//   old) -> writeV(t+1) -> compute(t) -> lgkmcnt(0) + raw s_barrier.
// Loads for t+2 stay in flight ACROSS the barrier; vmcnt(0) only at segment
// prologue. Tail staging clamped to keep the vmcnt literal uniform.
// exp -> exp2 (log2e folded into Q scale); setprio(1) around MFMA clusters.
#define VROW 32
__global__ __launch_bounds__(256) void attn_swa(const bf16_t* __restrict__ Q,
                                                const bf16_t* __restrict__ K,
                                                const bf16_t* __restrict__ Vt,
                                                bf16_t* __restrict__ Y) {
  __shared__ __align__(16) bf16_t Ks[3 * 32 * 128];
  __shared__ __align__(16) bf16_t Vs[3 * 128 * VROW];

  const int tid = threadIdx.x;
  const int lane = tid & 63;
  const int w = tid >> 6;
  const int lr = lane & 15, lc = lane >> 4;
  const int b = blockIdx.z, h = blockIdx.y;
  const int g = h >> 2;

  // segment list: blockIdx.x<16 -> heavy tile x+16; else light pair (p,15-p)
  int nseg, sx0, sx1 = 0;
  if (blockIdx.x < 16) {
    nseg = 1;
    sx0 = blockIdx.x + 16;
  } else {
    nseg = 2;
    sx0 = blockIdx.x - 16;
    sx1 = 15 - sx0;
  }

  const bf16_t* Qp = Q + ((size_t)(b * 16 + h) * 2048) * 128;
  const bf16_t* Kp = K + ((size_t)(b * 4 + g) * 2048) * 128;
  const bf16_t* Vp = Vt + ((size_t)(b * 4 + g) * 128) * 2048;

  // K chunk: row (tid>>4), src col XOR-preswizzled (dest linear)
  const int kmj = tid >> 4;
  const int kmc = ((tid & 15) ^ (kmj & 7)) * 8;
  const bf16_t* Ksrc = Kp + (size_t)kmj * 128 + kmc;
  // V chunk: d = tid>>2 (+64 for chunk1), vc = tid&3
  const int vd = tid >> 2, vc = tid & 3;
  const bf16_t* Vsrc = Vp + (size_t)vd * 2048 + vc * 8;
  const int vdst = vd * VROW + (vc & 1) * 16 + (vc >> 1) * 4;

  auto stageK = [&](int bufi, int j0) {
    const bf16_t* s = Ksrc + (size_t)j0 * 128;
    __builtin_amdgcn_global_load_lds((glb_u32_t*)s,
                                     (lds_u32_t*)(Ks + bufi * 4096 + w * 512), 16, 0, 0);
    __builtin_amdgcn_global_load_lds((glb_u32_t*)(s + 16 * 128),
                                     (lds_u32_t*)(Ks + bufi * 4096 + 2048 + w * 512), 16, 0, 0);
  };
  auto loadV = [&](int j0, uint4& a, uint4& bqv) {
    a = *reinterpret_cast<const uint4*>(Vsrc + j0);
    bqv = *reinterpret_cast<const uint4*>(Vsrc + 64 * 2048 + j0);
  };
  auto writeV = [&](int bufi, uint4 a, uint4 bqv) {
    bf16_t* p = Vs + bufi * 128 * VROW + vdst;
    *reinterpret_cast<uint2*>(p) = make_uint2(a.x, a.y);
    *reinterpret_cast<uint2*>(p + 8) = make_uint2(a.z, a.w);
    bf16_t* p1 = p + 64 * VROW;
    *reinterpret_cast<uint2*>(p1) = make_uint2(bqv.x, bqv.y);
    *reinterpret_cast<uint2*>(p1 + 8) = make_uint2(bqv.z, bqv.w);
  };

  const int kxor = (lr & 7) << 4;

  for (int sidx = 0; sidx < nseg; ++sidx) {
    const int i0b = ((sidx == 0) ? sx0 : sx1) * 64;
    const int i0 = i0b + w * 16;
    const int qrow = i0 + lr;

    bf16x8 qf[4];
#pragma unroll
    for (int kc = 0; kc < 4; ++kc)
      qf[kc] = *reinterpret_cast<const bf16x8*>(&Qp[(size_t)qrow * 128 + kc * 32 + lc * 8]);

    f32x4 o[8] = {};
    float mrun = -1e30f, lrun = 0.f;

    int lo = i0b - 1023;
    if (lo < 0) lo = 0;
    const int jstart = lo & ~31;
    const int jlast = i0b + 32;
    const int ntiles = (jlast - jstart) / 32 + 1;
    auto jof = [&](int t) { return jstart + 32 * (t < ntiles ? t : ntiles - 1); };

    // ---- prologue: drain leftovers, stage tiles 0 and 1 ----
    asm volatile("s_waitcnt vmcnt(0)");
    uint4 vAa, vAb, vBa, vBb;
    stageK(0, jof(0));
    loadV(jof(0), vAa, vAb);
    stageK(1, jof(1));
    loadV(jof(1), vBa, vBb);
    asm volatile("s_waitcnt vmcnt(4)");  // tile0's 4 ops done (tile1's in flight)
    writeV(0, vAa, vAb);
    vAa = vBa; vAb = vBb;
    asm volatile("s_waitcnt lgkmcnt(0)" ::: "memory");
    __builtin_amdgcn_s_barrier();

    int bc = 0, bn1 = 1, bn2 = 2;  // LDS buffers for tiles t, t+1, t+2
    for (int t = 0; t < ntiles; ++t) {
      // issue stage for tile t+2 (clamped at tail to keep vmcnt uniform)
      stageK(bn2, jof(t + 2));
      loadV(jof(t + 2), vBa, vBb);
      // tile t+1's 4 vm ops were issued one full iteration ago -> cheap wait
      asm volatile("s_waitcnt vmcnt(4)");
      writeV(bn1, vAa, vAb);
      vAa = vBa; vAb = vBb;

      const int j0 = jstart + 32 * t;
      const bool active = (j0 <= i0 + 15) && (j0 + 31 > i0 - 1024);
      if (active) {
        const bf16_t* Kb = Ks + bc * 4096;
        const bf16_t* Vb = Vs + bc * 128 * VROW;
        // S^T = K * Q^T (S in log2 units; scale*log2e folded into Q)
        f32x4 s0 = {}, s1 = {};
        __builtin_amdgcn_s_setprio(1);
#pragma unroll
        for (int kc = 0; kc < 4; ++kc) {
          int col = ((kc * 64 + lc * 16) ^ kxor) >> 1;
          bf16x8 kf0 = *reinterpret_cast<const bf16x8*>(Kb + lr * 128 + col);
          bf16x8 kf1 = *reinterpret_cast<const bf16x8*>(Kb + (16 + lr) * 128 + col);
          s0 = __builtin_amdgcn_mfma_f32_16x16x32_bf16(kf0, qf[kc], s0, 0, 0, 0);
          s1 = __builtin_amdgcn_mfma_f32_16x16x32_bf16(kf1, qf[kc], s1, 0, 0, 0);
        }
        __builtin_amdgcn_s_setprio(0);
        bf16x8 vvf[8];
#pragma unroll
        for (int f = 0; f < 8; ++f)
          vvf[f] = *reinterpret_cast<const bf16x8*>(Vb + (f * 16 + lr) * VROW + lc * 8);

        // masking (skipped on wave-uniform interior tiles)
        const bool full = (j0 + 31 <= i0) && (j0 >= i0 - 1008);
        float rm;
        if (full) {
          rm = fmaxf(fmaxf(fmaxf(s0[0], s0[1]), fmaxf(s0[2], s0[3])),
                     fmaxf(fmaxf(s1[0], s1[1]), fmaxf(s1[2], s1[3])));
        } else {
          rm = -1e30f;
#pragma unroll
          for (int r = 0; r < 4; ++r) {
            int ja = j0 + lc * 4 + r;
            int jb = ja + 16;
            bool oka = (ja <= qrow) && (ja > qrow - 1024);
            bool okb = (jb <= qrow) && (jb > qrow - 1024);
            float sa = oka ? s0[r] : -1e30f;
            float sb = okb ? s1[r] : -1e30f;
            s0[r] = sa;
            s1[r] = sb;
            rm = fmaxf(rm, fmaxf(sa, sb));
          }
        }
        rm = fmaxf(rm, __shfl_xor(rm, 16));
        rm = fmaxf(rm, __shfl_xor(rm, 32));

        // defer-max (T13): 11.5 log2-units ~= 8 nats
        if (!__all(rm <= mrun + 11.5f)) {
          float mnew = fmaxf(mrun, rm);
          float alpha = exp2f(mrun - mnew);
          mrun = mnew;
          lrun *= alpha;
#pragma unroll
          for (int f = 0; f < 8; ++f)
#pragma unroll
            for (int r = 0; r < 4; ++r) o[f][r] *= alpha;
        }

        // P = exp2(S - mrun); masked slots exactly 0
        float p0[4], p1[4], ps = 0.f;
#pragma unroll
        for (int r = 0; r < 4; ++r) {
          p0[r] = exp2f(s0[r] - mrun);
          p1[r] = exp2f(s1[r] - mrun);
          ps += p0[r] + p1[r];
        }
        ps += __shfl_xor(ps, 16);
        ps += __shfl_xor(ps, 32);
        lrun += ps;

        bf16_t pb[8];
#pragma unroll
        for (int r = 0; r < 4; ++r) {
          pb[r] = __float2bfloat16(p0[r]);
          pb[r + 4] = __float2bfloat16(p1[r]);
        }
        bf16x8 pfrag = *reinterpret_cast<bf16x8*>(pb);

        __builtin_amdgcn_s_setprio(1);
#pragma unroll
        for (int f = 0; f < 8; ++f)
          o[f] = __builtin_amdgcn_mfma_f32_16x16x32_bf16(vvf[f], pfrag, o[f], 0, 0, 0);
        __builtin_amdgcn_s_setprio(0);
      }

      // writer-side LDS drain, then raw barrier: t+2's vm ops stay in flight
      asm volatile("s_waitcnt lgkmcnt(0)" ::: "memory");
      __builtin_amdgcn_s_barrier();
      int tmp = bc; bc = bn1; bn1 = bn2; bn2 = tmp;
    }

    float inv = 1.f / lrun;
#pragma unroll
    for (int f = 0; f < 8; ++f) {
      bf16_t ob[4];
#pragma unroll
      for (int r = 0; r < 4; ++r) ob[r] = __float2bfloat16(o[f][r] * inv);
      *reinterpret_cast<uint2*>(
          &Y[((size_t)(b * 2048 + qrow)) * 2048 + h * 128 + f * 16 + lc * 4]) =
          *reinterpret_cast<uint2*>(ob);
    }
  }
}

// ---------------- launch ----------------
extern "C" void kernel_launch(void* const* d_in, const int* in_sizes, int n_in,
                              void* d_out, int out_size, void* d_ws, size_t ws_size,
                              hipStream_t stream) {
  const float* x = (const float*)d_in[0];
  const float* cosp = (const float*)d_in[1];
  const float* sinp = (const float*)d_in[2];
  const float* Wa = (const float*)d_in[3];
  const float* Wp = (const float*)d_in[4];
  float* out = (float*)d_out;

  bf16_t* ws = (bf16_t*)d_ws;
  bf16_t* xb = ws;                  // x bf16 -> reused as Q
  bf16_t* wab = ws + 8388608;       // W_attn bf16 -> reused as K,V
  bf16_t* wpb = ws + 14680064;      // W_proj bf16
  bf16_t* qkv = ws + 18874368;      // qkv bf16 -> reused as Y,Vt
  bf16_t* Q = xb;                   // [B][H][T][HS]
  bf16_t* Kr = wab;                 // [B][G][T][HS]
  bf16_t* V = wab + 2097152;        // [B][G][T][HS]
  bf16_t* Y = qkv;                  // [B][T][H][HS]
  bf16_t* Vt = qkv + 8388608;       // [B][G][HS][T]

  cvt_f32_to_bf16<<<4096, 256, 0, stream>>>(x, xb, 1048576);
  cvt_f32_to_bf16<<<3072, 256, 0, stream>>>(Wa, wab, 786432);
  cvt_f32_to_bf16<<<2048, 256, 0, stream>>>(Wp, wpb, 524288);

  gemm_bt<bf16_t><<<dim3(24, 32), 256, 0, stream>>>(xb, wab, qkv, 4096, 3072, 2048);

  rope_scatter<<<4096, 256, 0, stream>>>(qkv, cosp, sinp, Q, Kr, V);

  transpose_v<<<dim3(64, 4, 8), dim3(32, 8), 0, stream>>>(V, Vt);

  attn_swa<<<dim3(24, 16, 2), 256, 0, stream>>>(Q, Kr, Vt, Y);

  gemm_bt<float><<<dim3(16, 32), 256, 0, stream>>>(Y, wpb, out, 4096, 2048, 2048);
}

// Round 9
// 253.191 us; speedup vs baseline: 1.0794x; 1.0794x over previous
//
#include <hip/hip_runtime.h>
#include <hip/hip_bf16.h>
#include <cstdint>
#include <type_traits>

using bf16_t = __hip_bfloat16;
typedef __bf16 bf16x8 __attribute__((ext_vector_type(8)));
typedef float f32x4 __attribute__((ext_vector_type(4)));

typedef __attribute__((address_space(3))) uint32_t lds_u32_t;
typedef const __attribute__((address_space(1))) uint32_t glb_u32_t;

// ---------------- f32 -> bf16 convert, 8 elems/thread ----------------
__global__ void cvt_f32_to_bf16(const float* __restrict__ in, bf16_t* __restrict__ out, int n8) {
  int stride = gridDim.x * blockDim.x;
  for (int i = blockIdx.x * blockDim.x + threadIdx.x; i < n8; i += stride) {
    const float4* p = reinterpret_cast<const float4*>(in) + (size_t)i * 2;
    float4 a = p[0];
    float4 b = p[1];
    bf16_t o[8];
    o[0] = __float2bfloat16(a.x); o[1] = __float2bfloat16(a.y);
    o[2] = __float2bfloat16(a.z); o[3] = __float2bfloat16(a.w);
    o[4] = __float2bfloat16(b.x); o[5] = __float2bfloat16(b.y);
    o[6] = __float2bfloat16(b.z); o[7] = __float2bfloat16(b.w);
    *reinterpret_cast<uint4*>(out + (size_t)i * 8) = *reinterpret_cast<const uint4*>(o);
  }
}

// ---------------- bf16 GEMM: C[M,N] = A[M,K] * Bt[N,K]^T ----------------
// 128x128 tile, BK=32, 4 waves (2x2 of 64x64), mfma_f32_16x16x32_bf16.
// Staging via global_load_lds width=16 (m97 pattern), 2-barrier K-loop.
template <typename OutT>
__global__ __launch_bounds__(256) void gemm_bt(const bf16_t* __restrict__ A,
                                               const bf16_t* __restrict__ Bt,
                                               OutT* __restrict__ C,
                                               int M, int N, int K) {
  __shared__ __align__(16) bf16_t As[128 * 32];
  __shared__ __align__(16) bf16_t Bs[128 * 32];
  const int tid = threadIdx.x;
  const int lane = tid & 63;
  const int w = tid >> 6;
  const int wm = w >> 1, wn = w & 1;
  const int lr = lane & 15, lc = lane >> 4;
  const int m0 = blockIdx.y * 128, n0 = blockIdx.x * 128;

  const int c0 = tid, c1 = tid + 256;
  const bf16_t* a0p = A + (size_t)(m0 + (c0 >> 2)) * K + (c0 & 3) * 8;
  const bf16_t* a1p = A + (size_t)(m0 + (c1 >> 2)) * K + (c1 & 3) * 8;
  const bf16_t* b0p = Bt + (size_t)(n0 + (c0 >> 2)) * K + (c0 & 3) * 8;
  const bf16_t* b1p = Bt + (size_t)(n0 + (c1 >> 2)) * K + (c1 & 3) * 8;

  bf16_t* asb0 = As + w * 512;
  bf16_t* asb1 = As + 2048 + w * 512;
  bf16_t* bsb0 = Bs + w * 512;
  bf16_t* bsb1 = Bs + 2048 + w * 512;

  f32x4 acc[4][4] = {};

  for (int k0 = 0; k0 < K; k0 += 32) {
    __syncthreads();
    __builtin_amdgcn_global_load_lds((glb_u32_t*)(a0p + k0), (lds_u32_t*)asb0, 16, 0, 0);
    __builtin_amdgcn_global_load_lds((glb_u32_t*)(a1p + k0), (lds_u32_t*)asb1, 16, 0, 0);
    __builtin_amdgcn_global_load_lds((glb_u32_t*)(b0p + k0), (lds_u32_t*)bsb0, 16, 0, 0);
    __builtin_amdgcn_global_load_lds((glb_u32_t*)(b1p + k0), (lds_u32_t*)bsb1, 16, 0, 0);
    __syncthreads();

    bf16x8 af[4], bfv[4];
#pragma unroll
    for (int i = 0; i < 4; ++i)
      af[i] = *reinterpret_cast<const bf16x8*>(&As[(wm * 64 + i * 16 + lr) * 32 + lc * 8]);
#pragma unroll
    for (int i = 0; i < 4; ++i)
      bfv[i] = *reinterpret_cast<const bf16x8*>(&Bs[(wn * 64 + i * 16 + lr) * 32 + lc * 8]);
#pragma unroll
    for (int i = 0; i < 4; ++i)
#pragma unroll
      for (int j = 0; j < 4; ++j)
        acc[i][j] = __builtin_amdgcn_mfma_f32_16x16x32_bf16(af[i], bfv[j], acc[i][j], 0, 0, 0);
  }

#pragma unroll
  for (int i = 0; i < 4; ++i)
#pragma unroll
    for (int j = 0; j < 4; ++j) {
      int row = m0 + wm * 64 + i * 16 + lc * 4;
      int col = n0 + wn * 64 + j * 16 + lr;
#pragma unroll
      for (int r = 0; r < 4; ++r) {
        float v = acc[i][j][r];
        if constexpr (std::is_same<OutT, float>::value)
          C[(size_t)(row + r) * N + col] = v;
        else
          C[(size_t)(row + r) * N + col] = __float2bfloat16(v);
      }
    }
}

// ---------------- RoPE + scatter qkv -> Q (scaled), K, V ----------------
__global__ __launch_bounds__(256) void rope_scatter(const bf16_t* __restrict__ qkv,
                                                    const float* __restrict__ cosp,
                                                    const float* __restrict__ sinp,
                                                    bf16_t* __restrict__ Q,
                                                    bf16_t* __restrict__ K,
                                                    bf16_t* __restrict__ V) {
  const int row = blockIdx.x;  // b*2048 + t
  const int b = row >> 11, t = row & 2047;
  const bf16_t* src = qkv + (size_t)row * 3072;
  for (int n = threadIdx.x; n < 3072; n += 256) {
    int g = n / 768;
    int r = n - g * 768;
    int slot = r >> 7;
    int d = r & 127;
    if (slot == 5) {
      V[(((size_t)(b * 4 + g)) * 2048 + t) * 128 + d] = src[n];
    } else {
      float v = __bfloat162float(src[n]);
      float other = __bfloat162float(src[n ^ 64]);
      float c = cosp[t * 128 + d];
      float s = sinp[t * 128 + d];
      float rot = (d < 64) ? -other : other;
      float res = v * c + rot * s;
      if (slot < 4) {
        int h = g * 4 + slot;
        // fold softmax scale 1/sqrt(128) AND log2(e) into Q (attn uses exp2)
        Q[(((size_t)(b * 16 + h)) * 2048 + t) * 128 + d] =
            __float2bfloat16(res * (0.08838834764831843f * 1.4426950408889634f));
      } else {
        K[(((size_t)(b * 4 + g)) * 2048 + t) * 128 + d] = __float2bfloat16(res);
      }
    }
  }
}

// ---------------- V [bg][t][d] -> Vt [bg][d][t] ----------------
__global__ void transpose_v(const bf16_t* __restrict__ V, bf16_t* __restrict__ Vt) {
  __shared__ bf16_t tile[32][33];
  const int bg = blockIdx.z;
  const int t0 = blockIdx.x * 32;
  const int d0 = blockIdx.y * 32;
  const bf16_t* src = V + (size_t)bg * 2048 * 128;
  bf16_t* dst = Vt + (size_t)bg * 128 * 2048;
#pragma unroll
  for (int i = threadIdx.y; i < 32; i += 8)
    tile[i][threadIdx.x] = src[(size_t)(t0 + i) * 128 + d0 + threadIdx.x];
  __syncthreads();
#pragma unroll
  for (int i = threadIdx.y; i < 32; i += 8)
    dst[(size_t)(d0 + i) * 2048 + t0 + threadIdx.x] = tile[threadIdx.x][i];
}

// ---------------- sliding-window flash attention (v9) --------------------
// Round-7 structure (2-phase dbuf, equalized 24-block grid) + SHUFFLE-FREE
// steady-state softmax:
//  - T13 trigger checked on LANE-PARTIAL max via __all (wave vote, no shfl);
//    cross-lane max + rescale only on the rare trigger (group-uniform mrun
//    preserved by induction).
//  - lrun kept lane-partial; single 2-shfl reduction at epilogue.
// Removes 4 serial ds_swizzle (~120cy each) + waits from EVERY tile.
// exp2 math (scale*log2e folded into Q); setprio(1) around MFMA clusters.
#define VROW 40
__global__ __launch_bounds__(256) void attn_swa(const bf16_t* __restrict__ Q,
                                                const bf16_t* __restrict__ K,
                                                const bf16_t* __restrict__ Vt,
                                                bf16_t* __restrict__ Y) {
  __shared__ __align__(16) bf16_t Ks[2 * 32 * 128];
  __shared__ __align__(16) bf16_t Vs[2 * 128 * VROW];

  const int tid = threadIdx.x;
  const int lane = tid & 63;
  const int w = tid >> 6;
  const int lr = lane & 15, lc = lane >> 4;
  const int b = blockIdx.z, h = blockIdx.y;
  const int g = h >> 2;

  // segment list: blockIdx.x<16 -> heavy tile x+16; else light pair (p,15-p)
  int nseg, sx0, sx1 = 0;
  if (blockIdx.x < 16) {
    nseg = 1;
    sx0 = blockIdx.x + 16;
  } else {
    nseg = 2;
    sx0 = blockIdx.x - 16;
    sx1 = 15 - sx0;
  }

  const bf16_t* Qp = Q + ((size_t)(b * 16 + h) * 2048) * 128;
  const bf16_t* Kp = K + ((size_t)(b * 4 + g) * 2048) * 128;
  const bf16_t* Vp = Vt + ((size_t)(b * 4 + g) * 128) * 2048;

  // K chunk: row (tid>>4), src col XOR-preswizzled (dest linear)
  const int kmj = tid >> 4;
  const int kmc = ((tid & 15) ^ (kmj & 7)) * 8;
  const bf16_t* Ksrc = Kp + (size_t)kmj * 128 + kmc;
  // V chunk: d = tid>>2 (+64 for chunk1), vc = tid&3
  const int vd = tid >> 2, vc = tid & 3;
  const bf16_t* Vsrc = Vp + (size_t)vd * 2048 + vc * 8;
  const int vdst = vd * VROW + (vc & 1) * 16 + (vc >> 1) * 4;

  auto stageK = [&](int bufi, int j0) {
    const bf16_t* s = Ksrc + (size_t)j0 * 128;
    __builtin_amdgcn_global_load_lds((glb_u32_t*)s,
                                     (lds_u32_t*)(Ks + bufi * 4096 + w * 512), 16, 0, 0);
    __builtin_amdgcn_global_load_lds((glb_u32_t*)(s + 16 * 128),
                                     (lds_u32_t*)(Ks + bufi * 4096 + 2048 + w * 512), 16, 0, 0);
  };
  auto loadV = [&](int j0, uint4& a, uint4& bqv) {
    a = *reinterpret_cast<const uint4*>(Vsrc + j0);
    bqv = *reinterpret_cast<const uint4*>(Vsrc + 64 * 2048 + j0);
  };
  auto writeV = [&](int bufi, uint4 a, uint4 bqv) {
    bf16_t* p = Vs + bufi * 128 * VROW + vdst;
    *reinterpret_cast<uint2*>(p) = make_uint2(a.x, a.y);
    *reinterpret_cast<uint2*>(p + 8) = make_uint2(a.z, a.w);
    bf16_t* p1 = p + 64 * VROW;
    *reinterpret_cast<uint2*>(p1) = make_uint2(bqv.x, bqv.y);
    *reinterpret_cast<uint2*>(p1 + 8) = make_uint2(bqv.z, bqv.w);
  };

  const int kxor = (lr & 7) << 4;

  for (int sidx = 0; sidx < nseg; ++sidx) {
    const int i0b = ((sidx == 0) ? sx0 : sx1) * 64;
    const int i0 = i0b + w * 16;
    const int qrow = i0 + lr;

    bf16x8 qf[4];
#pragma unroll
    for (int kc = 0; kc < 4; ++kc)
      qf[kc] = *reinterpret_cast<const bf16x8*>(&Qp[(size_t)qrow * 128 + kc * 32 + lc * 8]);

    f32x4 o[8] = {};
    float mrun = -1e30f, lrun = 0.f;  // lrun is LANE-PARTIAL (reduced at epilogue)

    int lo = i0b - 1023;
    if (lo < 0) lo = 0;
    const int jstart = lo & ~31;
    const int jlast = i0b + 32;

    {
      stageK(0, jstart);
      uint4 va, vb;
      loadV(jstart, va, vb);
      writeV(0, va, vb);
    }
    __syncthreads();

    int buf = 0;
    for (int j0 = jstart; j0 <= jlast; j0 += 32) {
      const int nxt = j0 + 32;
      uint4 va, vb;
      const bool do_stage = (nxt <= jlast);
      if (do_stage) {
        stageK(buf ^ 1, nxt);
        loadV(nxt, va, vb);
      }

      const bool active = (j0 <= i0 + 15) && (j0 + 31 > i0 - 1024);
      if (active) {
        const bf16_t* Kb = Ks + buf * 4096;
        const bf16_t* Vb = Vs + buf * 128 * VROW;
        // S^T = K * Q^T  (log2 units; scale*log2e folded into Q)
        f32x4 s0 = {}, s1 = {};
        __builtin_amdgcn_s_setprio(1);
#pragma unroll
        for (int kc = 0; kc < 4; ++kc) {
          int col = ((kc * 64 + lc * 16) ^ kxor) >> 1;
          bf16x8 kf0 = *reinterpret_cast<const bf16x8*>(Kb + lr * 128 + col);
          bf16x8 kf1 = *reinterpret_cast<const bf16x8*>(Kb + (16 + lr) * 128 + col);
          s0 = __builtin_amdgcn_mfma_f32_16x16x32_bf16(kf0, qf[kc], s0, 0, 0, 0);
          s1 = __builtin_amdgcn_mfma_f32_16x16x32_bf16(kf1, qf[kc], s1, 0, 0, 0);
        }
        __builtin_amdgcn_s_setprio(0);
        bf16x8 vvf[8];
#pragma unroll
        for (int f = 0; f < 8; ++f)
          vvf[f] = *reinterpret_cast<const bf16x8*>(Vb + (f * 16 + lr) * VROW + lc * 8);

        // masking (skipped on wave-uniform interior tiles)
        const bool full = (j0 + 31 <= i0) && (j0 >= i0 - 1008);
        if (!full) {
#pragma unroll
          for (int r = 0; r < 4; ++r) {
            int ja = j0 + lc * 4 + r;
            int jb = ja + 16;
            bool oka = (ja <= qrow) && (ja > qrow - 1024);
            bool okb = (jb <= qrow) && (jb > qrow - 1024);
            s0[r] = oka ? s0[r] : -1e30f;
            s1[r] = okb ? s1[r] : -1e30f;
          }
        }
        // lane-partial max (no cross-lane traffic)
        float rm = fmaxf(fmaxf(fmaxf(s0[0], s0[1]), fmaxf(s0[2], s0[3])),
                         fmaxf(fmaxf(s1[0], s1[1]), fmaxf(s1[2], s1[3])));

        // defer-max (T13, THR=11.5 log2-units): trigger check on partial max
        // is sound (all partials <= bound => row max <= bound). Rare path does
        // the cross-lane reduce; mrun stays lc-group-uniform by induction.
        if (!__all(rm <= mrun + 11.5f)) {
          rm = fmaxf(rm, __shfl_xor(rm, 16));
          rm = fmaxf(rm, __shfl_xor(rm, 32));
          float mnew = fmaxf(mrun, rm);
          float alpha = exp2f(mrun - mnew);
          mrun = mnew;
          lrun *= alpha;
#pragma unroll
          for (int f = 0; f < 8; ++f)
#pragma unroll
            for (int r = 0; r < 4; ++r) o[f][r] *= alpha;
        }

        // P = exp2(S - mrun); masked slots exactly 0; lrun lane-partial
        float p0[4], p1[4], ps = 0.f;
#pragma unroll
        for (int r = 0; r < 4; ++r) {
          p0[r] = exp2f(s0[r] - mrun);
          p1[r] = exp2f(s1[r] - mrun);
          ps += p0[r] + p1[r];
        }
        lrun += ps;

        bf16_t pb[8];
#pragma unroll
        for (int r = 0; r < 4; ++r) {
          pb[r] = __float2bfloat16(p0[r]);
          pb[r + 4] = __float2bfloat16(p1[r]);
        }
        bf16x8 pfrag = *reinterpret_cast<bf16x8*>(pb);

        __builtin_amdgcn_s_setprio(1);
#pragma unroll
        for (int f = 0; f < 8; ++f)
          o[f] = __builtin_amdgcn_mfma_f32_16x16x32_bf16(vvf[f], pfrag, o[f], 0, 0, 0);
        __builtin_amdgcn_s_setprio(0);
      }

      if (do_stage) writeV(buf ^ 1, va, vb);
      __syncthreads();
      buf ^= 1;
    }

    // epilogue: reduce lane-partial denominators across the lc group (2 shfl
    // per SEGMENT instead of 4 per tile), then normalize and store.
    float lt = lrun;
    lt += __shfl_xor(lt, 16);
    lt += __shfl_xor(lt, 32);
    float inv = 1.f / lt;
#pragma unroll
    for (int f = 0; f < 8; ++f) {
      bf16_t ob[4];
#pragma unroll
      for (int r = 0; r < 4; ++r) ob[r] = __float2bfloat16(o[f][r] * inv);
      *reinterpret_cast<uint2*>(
          &Y[((size_t)(b * 2048 + qrow)) * 2048 + h * 128 + f * 16 + lc * 4]) =
          *reinterpret_cast<uint2*>(ob);
    }
  }
}

// ---------------- launch ----------------
extern "C" void kernel_launch(void* const* d_in, const int* in_sizes, int n_in,
                              void* d_out, int out_size, void* d_ws, size_t ws_size,
                              hipStream_t stream) {
  const float* x = (const float*)d_in[0];
  const float* cosp = (const float*)d_in[1];
  const float* sinp = (const float*)d_in[2];
  const float* Wa = (const float*)d_in[3];
  const float* Wp = (const float*)d_in[4];
  float* out = (float*)d_out;

  bf16_t* ws = (bf16_t*)d_ws;
  bf16_t* xb = ws;                  // x bf16 -> reused as Q
  bf16_t* wab = ws + 8388608;       // W_attn bf16 -> reused as K,V
  bf16_t* wpb = ws + 14680064;      // W_proj bf16
  bf16_t* qkv = ws + 18874368;      // qkv bf16 -> reused as Y,Vt
  bf16_t* Q = xb;                   // [B][H][T][HS]
  bf16_t* Kr = wab;                 // [B][G][T][HS]
  bf16_t* V = wab + 2097152;        // [B][G][T][HS]
  bf16_t* Y = qkv;                  // [B][T][H][HS]
  bf16_t* Vt = qkv + 8388608;       // [B][G][HS][T]

  cvt_f32_to_bf16<<<4096, 256, 0, stream>>>(x, xb, 1048576);
  cvt_f32_to_bf16<<<3072, 256, 0, stream>>>(Wa, wab, 786432);
  cvt_f32_to_bf16<<<2048, 256, 0, stream>>>(Wp, wpb, 524288);

  gemm_bt<bf16_t><<<dim3(24, 32), 256, 0, stream>>>(xb, wab, qkv, 4096, 3072, 2048);

  rope_scatter<<<4096, 256, 0, stream>>>(qkv, cosp, sinp, Q, Kr, V);

  transpose_v<<<dim3(64, 4, 8), dim3(32, 8), 0, stream>>>(V, Vt);

  attn_swa<<<dim3(24, 16, 2), 256, 0, stream>>>(Q, Kr, Vt, Y);

  gemm_bt<float><<<dim3(16, 32), 256, 0, stream>>>(Y, wpb, out, 4096, 2048, 2048);
}

// Round 10
// 252.629 us; speedup vs baseline: 1.0818x; 1.0022x over previous
//
#include <hip/hip_runtime.h>
#include <hip/hip_bf16.h>
#include <cstdint>
#include <type_traits>

using bf16_t = __hip_bfloat16;
typedef __bf16 bf16x8 __attribute__((ext_vector_type(8)));
typedef float f32x4 __attribute__((ext_vector_type(4)));

typedef __attribute__((address_space(3))) uint32_t lds_u32_t;
typedef const __attribute__((address_space(1))) uint32_t glb_u32_t;

// ---------------- f32 -> bf16 convert, 8 elems/thread ----------------
__global__ void cvt_f32_to_bf16(const float* __restrict__ in, bf16_t* __restrict__ out, int n8) {
  int stride = gridDim.x * blockDim.x;
  for (int i = blockIdx.x * blockDim.x + threadIdx.x; i < n8; i += stride) {
    const float4* p = reinterpret_cast<const float4*>(in) + (size_t)i * 2;
    float4 a = p[0];
    float4 b = p[1];
    bf16_t o[8];
    o[0] = __float2bfloat16(a.x); o[1] = __float2bfloat16(a.y);
    o[2] = __float2bfloat16(a.z); o[3] = __float2bfloat16(a.w);
    o[4] = __float2bfloat16(b.x); o[5] = __float2bfloat16(b.y);
    o[6] = __float2bfloat16(b.z); o[7] = __float2bfloat16(b.w);
    *reinterpret_cast<uint4*>(out + (size_t)i * 8) = *reinterpret_cast<const uint4*>(o);
  }
}

// ---------------- bf16 GEMM: C[M,N] = A[M,K] * Bt[N,K]^T ----------------
// 128x128 tile, BK=32, 4 waves (2x2 of 64x64), mfma_f32_16x16x32_bf16.
// Staging via global_load_lds width=16 (m97 pattern), 2-barrier K-loop.
template <typename OutT>
__global__ __launch_bounds__(256) void gemm_bt(const bf16_t* __restrict__ A,
                                               const bf16_t* __restrict__ Bt,
                                               OutT* __restrict__ C,
                                               int M, int N, int K) {
  __shared__ __align__(16) bf16_t As[128 * 32];
  __shared__ __align__(16) bf16_t Bs[128 * 32];
  const int tid = threadIdx.x;
  const int lane = tid & 63;
  const int w = tid >> 6;
  const int wm = w >> 1, wn = w & 1;
  const int lr = lane & 15, lc = lane >> 4;
  const int m0 = blockIdx.y * 128, n0 = blockIdx.x * 128;

  const int c0 = tid, c1 = tid + 256;
  const bf16_t* a0p = A + (size_t)(m0 + (c0 >> 2)) * K + (c0 & 3) * 8;
  const bf16_t* a1p = A + (size_t)(m0 + (c1 >> 2)) * K + (c1 & 3) * 8;
  const bf16_t* b0p = Bt + (size_t)(n0 + (c0 >> 2)) * K + (c0 & 3) * 8;
  const bf16_t* b1p = Bt + (size_t)(n0 + (c1 >> 2)) * K + (c1 & 3) * 8;

  bf16_t* asb0 = As + w * 512;
  bf16_t* asb1 = As + 2048 + w * 512;
  bf16_t* bsb0 = Bs + w * 512;
  bf16_t* bsb1 = Bs + 2048 + w * 512;

  f32x4 acc[4][4] = {};

  for (int k0 = 0; k0 < K; k0 += 32) {
    __syncthreads();
    __builtin_amdgcn_global_load_lds((glb_u32_t*)(a0p + k0), (lds_u32_t*)asb0, 16, 0, 0);
    __builtin_amdgcn_global_load_lds((glb_u32_t*)(a1p + k0), (lds_u32_t*)asb1, 16, 0, 0);
    __builtin_amdgcn_global_load_lds((glb_u32_t*)(b0p + k0), (lds_u32_t*)bsb0, 16, 0, 0);
    __builtin_amdgcn_global_load_lds((glb_u32_t*)(b1p + k0), (lds_u32_t*)bsb1, 16, 0, 0);
    __syncthreads();

    bf16x8 af[4], bfv[4];
#pragma unroll
    for (int i = 0; i < 4; ++i)
      af[i] = *reinterpret_cast<const bf16x8*>(&As[(wm * 64 + i * 16 + lr) * 32 + lc * 8]);
#pragma unroll
    for (int i = 0; i < 4; ++i)
      bfv[i] = *reinterpret_cast<const bf16x8*>(&Bs[(wn * 64 + i * 16 + lr) * 32 + lc * 8]);
#pragma unroll
    for (int i = 0; i < 4; ++i)
#pragma unroll
      for (int j = 0; j < 4; ++j)
        acc[i][j] = __builtin_amdgcn_mfma_f32_16x16x32_bf16(af[i], bfv[j], acc[i][j], 0, 0, 0);
  }

#pragma unroll
  for (int i = 0; i < 4; ++i)
#pragma unroll
    for (int j = 0; j < 4; ++j) {
      int row = m0 + wm * 64 + i * 16 + lc * 4;
      int col = n0 + wn * 64 + j * 16 + lr;
#pragma unroll
      for (int r = 0; r < 4; ++r) {
        float v = acc[i][j][r];
        if constexpr (std::is_same<OutT, float>::value)
          C[(size_t)(row + r) * N + col] = v;
        else
          C[(size_t)(row + r) * N + col] = __float2bfloat16(v);
      }
    }
}

// ---------------- RoPE + scatter qkv -> Q (scaled), K, V ----------------
__global__ __launch_bounds__(256) void rope_scatter(const bf16_t* __restrict__ qkv,
                                                    const float* __restrict__ cosp,
                                                    const float* __restrict__ sinp,
                                                    bf16_t* __restrict__ Q,
                                                    bf16_t* __restrict__ K,
                                                    bf16_t* __restrict__ V) {
  const int row = blockIdx.x;  // b*2048 + t
  const int b = row >> 11, t = row & 2047;
  const bf16_t* src = qkv + (size_t)row * 3072;
  for (int n = threadIdx.x; n < 3072; n += 256) {
    int g = n / 768;
    int r = n - g * 768;
    int slot = r >> 7;
    int d = r & 127;
    if (slot == 5) {
      V[(((size_t)(b * 4 + g)) * 2048 + t) * 128 + d] = src[n];
    } else {
      float v = __bfloat162float(src[n]);
      float other = __bfloat162float(src[n ^ 64]);
      float c = cosp[t * 128 + d];
      float s = sinp[t * 128 + d];
      float rot = (d < 64) ? -other : other;
      float res = v * c + rot * s;
      if (slot < 4) {
        int h = g * 4 + slot;
        // fold softmax scale 1/sqrt(128) AND log2(e) into Q (attn uses exp2)
        Q[(((size_t)(b * 16 + h)) * 2048 + t) * 128 + d] =
            __float2bfloat16(res * (0.08838834764831843f * 1.4426950408889634f));
      } else {
        K[(((size_t)(b * 4 + g)) * 2048 + t) * 128 + d] = __float2bfloat16(res);
      }
    }
  }
}

// ---------------- V [bg][t][d] -> Vt [bg][d][t] ----------------
__global__ void transpose_v(const bf16_t* __restrict__ V, bf16_t* __restrict__ Vt) {
  __shared__ bf16_t tile[32][33];
  const int bg = blockIdx.z;
  const int t0 = blockIdx.x * 32;
  const int d0 = blockIdx.y * 32;
  const bf16_t* src = V + (size_t)bg * 2048 * 128;
  bf16_t* dst = Vt + (size_t)bg * 128 * 2048;
#pragma unroll
  for (int i = threadIdx.y; i < 32; i += 8)
    tile[i][threadIdx.x] = src[(size_t)(t0 + i) * 128 + d0 + threadIdx.x];
  __syncthreads();
#pragma unroll
  for (int i = threadIdx.y; i < 32; i += 8)
    dst[(size_t)(d0 + i) * 2048 + t0 + threadIdx.x] = tile[threadIdx.x][i];
}

// ---------------- sliding-window flash attention (v10) -------------------
// Round-9 math/layout, but K staging switched from global_load_lds to
// REG-STAGING (global->VGPR at iter top, ds_write just before the barrier).
// The barrier's implicit vmcnt(0) is now free (all vm ops consumed by the
// ds_writes, whose waitcnt sits ~600cy after issue, hidden under compute) --
// the barrier no longer waits on global memory (T14 async-STAGE split; HK /
// m214 attn pattern). LDS layout + swizzle + read side byte-identical.
#define VROW 40
__global__ __launch_bounds__(256) void attn_swa(const bf16_t* __restrict__ Q,
                                                const bf16_t* __restrict__ K,
                                                const bf16_t* __restrict__ Vt,
                                                bf16_t* __restrict__ Y) {
  __shared__ __align__(16) bf16_t Ks[2 * 32 * 128];
  __shared__ __align__(16) bf16_t Vs[2 * 128 * VROW];

  const int tid = threadIdx.x;
  const int lane = tid & 63;
  const int w = tid >> 6;
  const int lr = lane & 15, lc = lane >> 4;
  const int b = blockIdx.z, h = blockIdx.y;
  const int g = h >> 2;

  // segment list: blockIdx.x<16 -> heavy tile x+16; else light pair (p,15-p)
  int nseg, sx0, sx1 = 0;
  if (blockIdx.x < 16) {
    nseg = 1;
    sx0 = blockIdx.x + 16;
  } else {
    nseg = 2;
    sx0 = blockIdx.x - 16;
    sx1 = 15 - sx0;
  }

  const bf16_t* Qp = Q + ((size_t)(b * 16 + h) * 2048) * 128;
  const bf16_t* Kp = K + ((size_t)(b * 4 + g) * 2048) * 128;
  const bf16_t* Vp = Vt + ((size_t)(b * 4 + g) * 128) * 2048;

  // K chunk: row (tid>>4), src col XOR-preswizzled; LDS dest linear (tid*8
  // elems within each 16-row half) -- byte-identical layout to the old
  // global_load_lds staging, so the swizzled read side is unchanged.
  const int kmj = tid >> 4;
  const int kmc = ((tid & 15) ^ (kmj & 7)) * 8;
  const bf16_t* Ksrc = Kp + (size_t)kmj * 128 + kmc;
  // V chunk: d = tid>>2 (+64 for chunk1), vc = tid&3
  const int vd = tid >> 2, vc = tid & 3;
  const bf16_t* Vsrc = Vp + (size_t)vd * 2048 + vc * 8;
  const int vdst = vd * VROW + (vc & 1) * 16 + (vc >> 1) * 4;

  auto loadK = [&](int j0, uint4& ka, uint4& kb) {
    const bf16_t* s = Ksrc + (size_t)j0 * 128;
    ka = *reinterpret_cast<const uint4*>(s);
    kb = *reinterpret_cast<const uint4*>(s + 16 * 128);
  };
  auto writeK = [&](int bufi, uint4 ka, uint4 kb) {
    *reinterpret_cast<uint4*>(Ks + bufi * 4096 + tid * 8) = ka;
    *reinterpret_cast<uint4*>(Ks + bufi * 4096 + 2048 + tid * 8) = kb;
  };
  auto loadV = [&](int j0, uint4& a, uint4& bqv) {
    a = *reinterpret_cast<const uint4*>(Vsrc + j0);
    bqv = *reinterpret_cast<const uint4*>(Vsrc + 64 * 2048 + j0);
  };
  auto writeV = [&](int bufi, uint4 a, uint4 bqv) {
    bf16_t* p = Vs + bufi * 128 * VROW + vdst;
    *reinterpret_cast<uint2*>(p) = make_uint2(a.x, a.y);
    *reinterpret_cast<uint2*>(p + 8) = make_uint2(a.z, a.w);
    bf16_t* p1 = p + 64 * VROW;
    *reinterpret_cast<uint2*>(p1) = make_uint2(bqv.x, bqv.y);
    *reinterpret_cast<uint2*>(p1 + 8) = make_uint2(bqv.z, bqv.w);
  };

  const int kxor = (lr & 7) << 4;

  for (int sidx = 0; sidx < nseg; ++sidx) {
    const int i0b = ((sidx == 0) ? sx0 : sx1) * 64;
    const int i0 = i0b + w * 16;
    const int qrow = i0 + lr;

    bf16x8 qf[4];
#pragma unroll
    for (int kc = 0; kc < 4; ++kc)
      qf[kc] = *reinterpret_cast<const bf16x8*>(&Qp[(size_t)qrow * 128 + kc * 32 + lc * 8]);

    f32x4 o[8] = {};
    float mrun = -1e30f, lrun = 0.f;  // lrun LANE-PARTIAL (reduced at epilogue)

    int lo = i0b - 1023;
    if (lo < 0) lo = 0;
    const int jstart = lo & ~31;
    const int jlast = i0b + 32;

    {
      uint4 ka, kb, va, vb;
      loadK(jstart, ka, kb);
      loadV(jstart, va, vb);
      writeK(0, ka, kb);
      writeV(0, va, vb);
    }
    __syncthreads();

    int buf = 0;
    for (int j0 = jstart; j0 <= jlast; j0 += 32) {
      const int nxt = j0 + 32;
      uint4 ka, kb, va, vb;
      const bool do_stage = (nxt <= jlast);
      if (do_stage) {  // issue next tile's global loads FIRST (latency hides
        loadK(nxt, ka, kb);  // under this tile's compute; consumed by the
        loadV(nxt, va, vb);  // ds_writes AFTER compute)
      }

      const bool active = (j0 <= i0 + 15) && (j0 + 31 > i0 - 1024);
      if (active) {
        const bf16_t* Kb = Ks + buf * 4096;
        const bf16_t* Vb = Vs + buf * 128 * VROW;
        // S^T = K * Q^T  (log2 units; scale*log2e folded into Q)
        f32x4 s0 = {}, s1 = {};
        __builtin_amdgcn_s_setprio(1);
#pragma unroll
        for (int kc = 0; kc < 4; ++kc) {
          int col = ((kc * 64 + lc * 16) ^ kxor) >> 1;
          bf16x8 kf0 = *reinterpret_cast<const bf16x8*>(Kb + lr * 128 + col);
          bf16x8 kf1 = *reinterpret_cast<const bf16x8*>(Kb + (16 + lr) * 128 + col);
          s0 = __builtin_amdgcn_mfma_f32_16x16x32_bf16(kf0, qf[kc], s0, 0, 0, 0);
          s1 = __builtin_amdgcn_mfma_f32_16x16x32_bf16(kf1, qf[kc], s1, 0, 0, 0);
        }
        __builtin_amdgcn_s_setprio(0);
        bf16x8 vvf[8];
#pragma unroll
        for (int f = 0; f < 8; ++f)
          vvf[f] = *reinterpret_cast<const bf16x8*>(Vb + (f * 16 + lr) * VROW + lc * 8);

        // masking (skipped on wave-uniform interior tiles)
        const bool full = (j0 + 31 <= i0) && (j0 >= i0 - 1008);
        if (!full) {
#pragma unroll
          for (int r = 0; r < 4; ++r) {
            int ja = j0 + lc * 4 + r;
            int jb = ja + 16;
            bool oka = (ja <= qrow) && (ja > qrow - 1024);
            bool okb = (jb <= qrow) && (jb > qrow - 1024);
            s0[r] = oka ? s0[r] : -1e30f;
            s1[r] = okb ? s1[r] : -1e30f;
          }
        }
        // lane-partial max (no cross-lane traffic)
        float rm = fmaxf(fmaxf(fmaxf(s0[0], s0[1]), fmaxf(s0[2], s0[3])),
                         fmaxf(fmaxf(s1[0], s1[1]), fmaxf(s1[2], s1[3])));

        // defer-max (T13): trigger on partial max via wave vote; rare path
        // does the cross-lane reduce; mrun stays group-uniform by induction.
        if (!__all(rm <= mrun + 11.5f)) {
          rm = fmaxf(rm, __shfl_xor(rm, 16));
          rm = fmaxf(rm, __shfl_xor(rm, 32));
          float mnew = fmaxf(mrun, rm);
          float alpha = exp2f(mrun - mnew);
          mrun = mnew;
          lrun *= alpha;
#pragma unroll
          for (int f = 0; f < 8; ++f)
#pragma unroll
            for (int r = 0; r < 4; ++r) o[f][r] *= alpha;
        }

        // P = exp2(S - mrun); masked slots exactly 0; lrun lane-partial
        float p0[4], p1[4], ps = 0.f;
#pragma unroll
        for (int r = 0; r < 4; ++r) {
          p0[r] = exp2f(s0[r] - mrun);
          p1[r] = exp2f(s1[r] - mrun);
          ps += p0[r] + p1[r];
        }
        lrun += ps;

        bf16_t pb[8];
#pragma unroll
        for (int r = 0; r < 4; ++r) {
          pb[r] = __float2bfloat16(p0[r]);
          pb[r + 4] = __float2bfloat16(p1[r]);
        }
        bf16x8 pfrag = *reinterpret_cast<bf16x8*>(pb);

        __builtin_amdgcn_s_setprio(1);
#pragma unroll
        for (int f = 0; f < 8; ++f)
          o[f] = __builtin_amdgcn_mfma_f32_16x16x32_bf16(vvf[f], pfrag, o[f], 0, 0, 0);
        __builtin_amdgcn_s_setprio(0);
      }

      if (do_stage) {  // ds_writes AFTER compute: their implicit vmcnt wait
        writeK(buf ^ 1, ka, kb);  // lands here, not at the barrier
        writeV(buf ^ 1, va, vb);
      }
      __syncthreads();
      buf ^= 1;
    }

    // epilogue: reduce lane-partial denominators (2 shfl per SEGMENT)
    float lt = lrun;
    lt += __shfl_xor(lt, 16);
    lt += __shfl_xor(lt, 32);
    float inv = 1.f / lt;
#pragma unroll
    for (int f = 0; f < 8; ++f) {
      bf16_t ob[4];
#pragma unroll
      for (int r = 0; r < 4; ++r) ob[r] = __float2bfloat16(o[f][r] * inv);
      *reinterpret_cast<uint2*>(
          &Y[((size_t)(b * 2048 + qrow)) * 2048 + h * 128 + f * 16 + lc * 4]) =
          *reinterpret_cast<uint2*>(ob);
    }
  }
}

// ---------------- launch ----------------
extern "C" void kernel_launch(void* const* d_in, const int* in_sizes, int n_in,
                              void* d_out, int out_size, void* d_ws, size_t ws_size,
                              hipStream_t stream) {
  const float* x = (const float*)d_in[0];
  const float* cosp = (const float*)d_in[1];
  const float* sinp = (const float*)d_in[2];
  const float* Wa = (const float*)d_in[3];
  const float* Wp = (const float*)d_in[4];
  float* out = (float*)d_out;

  bf16_t* ws = (bf16_t*)d_ws;
  bf16_t* xb = ws;                  // x bf16 -> reused as Q
  bf16_t* wab = ws + 8388608;       // W_attn bf16 -> reused as K,V
  bf16_t* wpb = ws + 14680064;      // W_proj bf16
  bf16_t* qkv = ws + 18874368;      // qkv bf16 -> reused as Y,Vt
  bf16_t* Q = xb;                   // [B][H][T][HS]
  bf16_t* Kr = wab;                 // [B][G][T][HS]
  bf16_t* V = wab + 2097152;        // [B][G][T][HS]
  bf16_t* Y = qkv;                  // [B][T][H][HS]
  bf16_t* Vt = qkv + 8388608;       // [B][G][HS][T]

  cvt_f32_to_bf16<<<4096, 256, 0, stream>>>(x, xb, 1048576);
  cvt_f32_to_bf16<<<3072, 256, 0, stream>>>(Wa, wab, 786432);
  cvt_f32_to_bf16<<<2048, 256, 0, stream>>>(Wp, wpb, 524288);

  gemm_bt<bf16_t><<<dim3(24, 32), 256, 0, stream>>>(xb, wab, qkv, 4096, 3072, 2048);

  rope_scatter<<<4096, 256, 0, stream>>>(qkv, cosp, sinp, Q, Kr, V);

  transpose_v<<<dim3(64, 4, 8), dim3(32, 8), 0, stream>>>(V, Vt);

  attn_swa<<<dim3(24, 16, 2), 256, 0, stream>>>(Q, Kr, Vt, Y);

  gemm_bt<float><<<dim3(16, 32), 256, 0, stream>>>(Y, wpb, out, 4096, 2048, 2048);
}

// Round 11
// 246.803 us; speedup vs baseline: 1.1074x; 1.0236x over previous
//
#include <hip/hip_runtime.h>
#include <hip/hip_bf16.h>
#include <cstdint>
#include <type_traits>

using bf16_t = __hip_bfloat16;
typedef __bf16 bf16x8 __attribute__((ext_vector_type(8)));
typedef float f32x4 __attribute__((ext_vector_type(4)));

typedef __attribute__((address_space(3))) uint32_t lds_u32_t;
typedef const __attribute__((address_space(1))) uint32_t glb_u32_t;

// ---------------- f32 -> bf16 convert, 8 elems/thread ----------------
__global__ void cvt_f32_to_bf16(const float* __restrict__ in, bf16_t* __restrict__ out, int n8) {
  int stride = gridDim.x * blockDim.x;
  for (int i = blockIdx.x * blockDim.x + threadIdx.x; i < n8; i += stride) {
    const float4* p = reinterpret_cast<const float4*>(in) + (size_t)i * 2;
    float4 a = p[0];
    float4 b = p[1];
    bf16_t o[8];
    o[0] = __float2bfloat16(a.x); o[1] = __float2bfloat16(a.y);
    o[2] = __float2bfloat16(a.z); o[3] = __float2bfloat16(a.w);
    o[4] = __float2bfloat16(b.x); o[5] = __float2bfloat16(b.y);
    o[6] = __float2bfloat16(b.z); o[7] = __float2bfloat16(b.w);
    *reinterpret_cast<uint4*>(out + (size_t)i * 8) = *reinterpret_cast<const uint4*>(o);
  }
}

// ---------------- bf16 GEMM, 256x256 tile, 8-phase schedule --------------
// C[M,N] = A[M,K] * Bt[N,K]^T.  512 thr = 8 waves (2M x 4N), per-wave
// 128x64 output (acc[8][4] f32x4), BK=64, LDS 128 KiB double-buffered.
// T2: LDS XOR-swizzle byte^=(row&7)<<4, applied as pre-swizzled global
//     source (linear global_load_lds dest) + swizzled ds_read address.
// T3/T4: per-K-tile 4 phases {ds_read subtile | stage burst | raw barrier |
//     setprio(1) 16 MFMA setprio(0) | raw barrier}; next tile staged in
//     phases 0-1, single vmcnt(0) drain at tile boundary (loads get >=2
//     phases of compute cover; intra-phase barriers are raw, no vm drain).
// T1: bijective XCD swizzle (nwg % 8 == 0 for both call sites).
template <typename OutT>
__global__ __launch_bounds__(512, 2) void gemm256(const bf16_t* __restrict__ A,
                                                  const bf16_t* __restrict__ Bt,
                                                  OutT* __restrict__ C,
                                                  int M, int N, int K) {
  __shared__ __align__(16) bf16_t As[2 * 256 * 64];
  __shared__ __align__(16) bf16_t Bs[2 * 256 * 64];
  const int tid = threadIdx.x;
  const int lane = tid & 63;
  const int w = tid >> 6;          // 0..7
  const int wm = w >> 2, wn = w & 3;
  const int lr = lane & 15, lc = lane >> 4;

  // T1: XCD-aware bijective block swizzle (requires nwg % 8 == 0)
  const int nwg = gridDim.x * gridDim.y;
  const int orig = blockIdx.y * gridDim.x + blockIdx.x;
  const int cpx = nwg >> 3;
  const int swz = (orig & 7) * cpx + (orig >> 3);
  const int bx = swz % gridDim.x, by = swz / gridDim.x;
  const int m0 = by * 256, n0 = bx * 256;

  // staging geometry: chunk c = l*512 + tid covers LDS row c>>3, phys 16B
  // slot c&7; source column pre-swizzled so linear dest == swizzled layout.
  const int srow = tid >> 3;                       // 0..63 (+64 per load l)
  const int scol = ((tid & 7) ^ (srow & 7)) * 8;   // elems
  const bf16_t* Asrc = A + (size_t)(m0 + srow) * K + scol;
  const bf16_t* Bsrc = Bt + (size_t)(n0 + srow) * K + scol;

  f32x4 acc[8][4] = {};

  auto stageA = [&](int bufi, int kt) {
#pragma unroll
    for (int l = 0; l < 4; ++l)
      __builtin_amdgcn_global_load_lds(
          (glb_u32_t*)(Asrc + (size_t)kt * 64 + (size_t)l * 64 * K),
          (lds_u32_t*)(As + bufi * 16384 + l * 4096 + w * 512), 16, 0, 0);
  };
  auto stageB = [&](int bufi, int kt) {
#pragma unroll
    for (int l = 0; l < 4; ++l)
      __builtin_amdgcn_global_load_lds(
          (glb_u32_t*)(Bsrc + (size_t)kt * 64 + (size_t)l * 64 * K),
          (lds_u32_t*)(Bs + bufi * 16384 + l * 4096 + w * 512), 16, 0, 0);
  };

  const int nt = K >> 6;
  // prologue: stage K-tile 0 into buf 0
  stageA(0, 0);
  stageB(0, 0);
  asm volatile("s_waitcnt vmcnt(0)" ::: "memory");
  __builtin_amdgcn_s_barrier();

  bf16x8 a[4][2], bb[4][2];
  for (int t = 0; t < nt; ++t) {
    const int buf = t & 1;
    const char* Ab = (const char*)(As + buf * 16384);
    const char* Bb = (const char*)(Bs + buf * 16384);
    const bool st = (t + 1 < nt);

    auto rdA = [&](int i, int kk) {
      int R = wm * 128 + i * 16 + lr;
      return *reinterpret_cast<const bf16x8*>(
          Ab + R * 128 + ((kk * 64 + lc * 16) ^ ((R & 7) << 4)));
    };
    auto rdB = [&](int j, int kk) {
      int R = wn * 64 + j * 16 + lr;
      return *reinterpret_cast<const bf16x8*>(
          Bb + R * 128 + ((kk * 64 + lc * 16) ^ ((R & 7) << 4)));
    };

    // ---- phase 0: read A(i0-3) + B(j0-1); stage A(t+1); mfma i0-3 x j0-1
#pragma unroll
    for (int i = 0; i < 4; ++i) { a[i][0] = rdA(i, 0); a[i][1] = rdA(i, 1); }
#pragma unroll
    for (int j = 0; j < 2; ++j) { bb[j][0] = rdB(j, 0); bb[j][1] = rdB(j, 1); }
    if (st) stageA(buf ^ 1, t + 1);
    asm volatile("" ::: "memory");
    __builtin_amdgcn_s_barrier();
    __builtin_amdgcn_s_setprio(1);
#pragma unroll
    for (int i = 0; i < 4; ++i)
#pragma unroll
      for (int j = 0; j < 2; ++j) {
        acc[i][j] = __builtin_amdgcn_mfma_f32_16x16x32_bf16(a[i][0], bb[j][0], acc[i][j], 0, 0, 0);
        acc[i][j] = __builtin_amdgcn_mfma_f32_16x16x32_bf16(a[i][1], bb[j][1], acc[i][j], 0, 0, 0);
      }
    __builtin_amdgcn_s_setprio(0);
    asm volatile("" ::: "memory");
    __builtin_amdgcn_s_barrier();

    // ---- phase 1: read B(j2-3); stage B(t+1); mfma i0-3 x j2-3
#pragma unroll
    for (int j = 2; j < 4; ++j) { bb[j][0] = rdB(j, 0); bb[j][1] = rdB(j, 1); }
    if (st) stageB(buf ^ 1, t + 1);
    asm volatile("" ::: "memory");
    __builtin_amdgcn_s_barrier();
    __builtin_amdgcn_s_setprio(1);
#pragma unroll
    for (int i = 0; i < 4; ++i)
#pragma unroll
      for (int j = 2; j < 4; ++j) {
        acc[i][j] = __builtin_amdgcn_mfma_f32_16x16x32_bf16(a[i][0], bb[j][0], acc[i][j], 0, 0, 0);
        acc[i][j] = __builtin_amdgcn_mfma_f32_16x16x32_bf16(a[i][1], bb[j][1], acc[i][j], 0, 0, 0);
      }
    __builtin_amdgcn_s_setprio(0);
    asm volatile("" ::: "memory");
    __builtin_amdgcn_s_barrier();

    // ---- phase 2: read A(i4-7) (overwrite a[]); mfma i4-7 x j2-3
#pragma unroll
    for (int i = 0; i < 4; ++i) { a[i][0] = rdA(i + 4, 0); a[i][1] = rdA(i + 4, 1); }
    asm volatile("" ::: "memory");
    __builtin_amdgcn_s_barrier();
    __builtin_amdgcn_s_setprio(1);
#pragma unroll
    for (int i = 0; i < 4; ++i)
#pragma unroll
      for (int j = 2; j < 4; ++j) {
        acc[i + 4][j] = __builtin_amdgcn_mfma_f32_16x16x32_bf16(a[i][0], bb[j][0], acc[i + 4][j], 0, 0, 0);
        acc[i + 4][j] = __builtin_amdgcn_mfma_f32_16x16x32_bf16(a[i][1], bb[j][1], acc[i + 4][j], 0, 0, 0);
      }
    __builtin_amdgcn_s_setprio(0);
    asm volatile("" ::: "memory");
    __builtin_amdgcn_s_barrier();

    // ---- phase 3: mfma i4-7 x j0-1 (all operands resident)
    __builtin_amdgcn_s_setprio(1);
#pragma unroll
    for (int i = 0; i < 4; ++i)
#pragma unroll
      for (int j = 0; j < 2; ++j) {
        acc[i + 4][j] = __builtin_amdgcn_mfma_f32_16x16x32_bf16(a[i][0], bb[j][0], acc[i + 4][j], 0, 0, 0);
        acc[i + 4][j] = __builtin_amdgcn_mfma_f32_16x16x32_bf16(a[i][1], bb[j][1], acc[i + 4][j], 0, 0, 0);
      }
    __builtin_amdgcn_s_setprio(0);

    // ---- tile boundary: own ds_reads done (cheap), staged tile landed
    asm volatile("s_waitcnt lgkmcnt(0)" ::: "memory");
    asm volatile("s_waitcnt vmcnt(0)" ::: "memory");
    __builtin_amdgcn_s_barrier();
  }

  // epilogue: C/D layout col=lane&15, row=(lane>>4)*4+reg  [m89/m91]
#pragma unroll
  for (int i = 0; i < 8; ++i)
#pragma unroll
    for (int j = 0; j < 4; ++j) {
      int row = m0 + wm * 128 + i * 16 + lc * 4;
      int col = n0 + wn * 64 + j * 16 + lr;
#pragma unroll
      for (int r = 0; r < 4; ++r) {
        float v = acc[i][j][r];
        if constexpr (std::is_same<OutT, float>::value)
          C[(size_t)(row + r) * N + col] = v;
        else
          C[(size_t)(row + r) * N + col] = __float2bfloat16(v);
      }
    }
}

// ---------------- RoPE + scatter qkv -> Q (scaled), K, V ----------------
__global__ __launch_bounds__(256) void rope_scatter(const bf16_t* __restrict__ qkv,
                                                    const float* __restrict__ cosp,
                                                    const float* __restrict__ sinp,
                                                    bf16_t* __restrict__ Q,
                                                    bf16_t* __restrict__ K,
                                                    bf16_t* __restrict__ V) {
  const int row = blockIdx.x;  // b*2048 + t
  const int b = row >> 11, t = row & 2047;
  const bf16_t* src = qkv + (size_t)row * 3072;
  for (int n = threadIdx.x; n < 3072; n += 256) {
    int g = n / 768;
    int r = n - g * 768;
    int slot = r >> 7;
    int d = r & 127;
    if (slot == 5) {
      V[(((size_t)(b * 4 + g)) * 2048 + t) * 128 + d] = src[n];
    } else {
      float v = __bfloat162float(src[n]);
      float other = __bfloat162float(src[n ^ 64]);
      float c = cosp[t * 128 + d];
      float s = sinp[t * 128 + d];
      float rot = (d < 64) ? -other : other;
      float res = v * c + rot * s;
      if (slot < 4) {
        int h = g * 4 + slot;
        // fold softmax scale 1/sqrt(128) AND log2(e) into Q (attn uses exp2)
        Q[(((size_t)(b * 16 + h)) * 2048 + t) * 128 + d] =
            __float2bfloat16(res * (0.08838834764831843f * 1.4426950408889634f));
      } else {
        K[(((size_t)(b * 4 + g)) * 2048 + t) * 128 + d] = __float2bfloat16(res);
      }
    }
  }
}

// ---------------- V [bg][t][d] -> Vt [bg][d][t] ----------------
__global__ void transpose_v(const bf16_t* __restrict__ V, bf16_t* __restrict__ Vt) {
  __shared__ bf16_t tile[32][33];
  const int bg = blockIdx.z;
  const int t0 = blockIdx.x * 32;
  const int d0 = blockIdx.y * 32;
  const bf16_t* src = V + (size_t)bg * 2048 * 128;
  bf16_t* dst = Vt + (size_t)bg * 128 * 2048;
#pragma unroll
  for (int i = threadIdx.y; i < 32; i += 8)
    tile[i][threadIdx.x] = src[(size_t)(t0 + i) * 128 + d0 + threadIdx.x];
  __syncthreads();
#pragma unroll
  for (int i = threadIdx.y; i < 32; i += 8)
    dst[(size_t)(d0 + i) * 2048 + t0 + threadIdx.x] = tile[threadIdx.x][i];
}

// ---------------- sliding-window flash attention (v10, plateau) ----------
#define VROW 40
__global__ __launch_bounds__(256) void attn_swa(const bf16_t* __restrict__ Q,
                                                const bf16_t* __restrict__ K,
                                                const bf16_t* __restrict__ Vt,
                                                bf16_t* __restrict__ Y) {
  __shared__ __align__(16) bf16_t Ks[2 * 32 * 128];
  __shared__ __align__(16) bf16_t Vs[2 * 128 * VROW];

  const int tid = threadIdx.x;
  const int lane = tid & 63;
  const int w = tid >> 6;
  const int lr = lane & 15, lc = lane >> 4;
  const int b = blockIdx.z, h = blockIdx.y;
  const int g = h >> 2;

  // segment list: blockIdx.x<16 -> heavy tile x+16; else light pair (p,15-p)
  int nseg, sx0, sx1 = 0;
  if (blockIdx.x < 16) {
    nseg = 1;
    sx0 = blockIdx.x + 16;
  } else {
    nseg = 2;
    sx0 = blockIdx.x - 16;
    sx1 = 15 - sx0;
  }

  const bf16_t* Qp = Q + ((size_t)(b * 16 + h) * 2048) * 128;
  const bf16_t* Kp = K + ((size_t)(b * 4 + g) * 2048) * 128;
  const bf16_t* Vp = Vt + ((size_t)(b * 4 + g) * 128) * 2048;

  const int kmj = tid >> 4;
  const int kmc = ((tid & 15) ^ (kmj & 7)) * 8;
  const bf16_t* Ksrc = Kp + (size_t)kmj * 128 + kmc;
  const int vd = tid >> 2, vc = tid & 3;
  const bf16_t* Vsrc = Vp + (size_t)vd * 2048 + vc * 8;
  const int vdst = vd * VROW + (vc & 1) * 16 + (vc >> 1) * 4;

  auto loadK = [&](int j0, uint4& ka, uint4& kb) {
    const bf16_t* s = Ksrc + (size_t)j0 * 128;
    ka = *reinterpret_cast<const uint4*>(s);
    kb = *reinterpret_cast<const uint4*>(s + 16 * 128);
  };
  auto writeK = [&](int bufi, uint4 ka, uint4 kb) {
    *reinterpret_cast<uint4*>(Ks + bufi * 4096 + tid * 8) = ka;
    *reinterpret_cast<uint4*>(Ks + bufi * 4096 + 2048 + tid * 8) = kb;
  };
  auto loadV = [&](int j0, uint4& a, uint4& bqv) {
    a = *reinterpret_cast<const uint4*>(Vsrc + j0);
    bqv = *reinterpret_cast<const uint4*>(Vsrc + 64 * 2048 + j0);
  };
  auto writeV = [&](int bufi, uint4 a, uint4 bqv) {
    bf16_t* p = Vs + bufi * 128 * VROW + vdst;
    *reinterpret_cast<uint2*>(p) = make_uint2(a.x, a.y);
    *reinterpret_cast<uint2*>(p + 8) = make_uint2(a.z, a.w);
    bf16_t* p1 = p + 64 * VROW;
    *reinterpret_cast<uint2*>(p1) = make_uint2(bqv.x, bqv.y);
    *reinterpret_cast<uint2*>(p1 + 8) = make_uint2(bqv.z, bqv.w);
  };

  const int kxor = (lr & 7) << 4;

  for (int sidx = 0; sidx < nseg; ++sidx) {
    const int i0b = ((sidx == 0) ? sx0 : sx1) * 64;
    const int i0 = i0b + w * 16;
    const int qrow = i0 + lr;

    bf16x8 qf[4];
#pragma unroll
    for (int kc = 0; kc < 4; ++kc)
      qf[kc] = *reinterpret_cast<const bf16x8*>(&Qp[(size_t)qrow * 128 + kc * 32 + lc * 8]);

    f32x4 o[8] = {};
    float mrun = -1e30f, lrun = 0.f;  // lrun LANE-PARTIAL (reduced at epilogue)

    int lo = i0b - 1023;
    if (lo < 0) lo = 0;
    const int jstart = lo & ~31;
    const int jlast = i0b + 32;

    {
      uint4 ka, kb, va, vb;
      loadK(jstart, ka, kb);
      loadV(jstart, va, vb);
      writeK(0, ka, kb);
      writeV(0, va, vb);
    }
    __syncthreads();

    int buf = 0;
    for (int j0 = jstart; j0 <= jlast; j0 += 32) {
      const int nxt = j0 + 32;
      uint4 ka, kb, va, vb;
      const bool do_stage = (nxt <= jlast);
      if (do_stage) {
        loadK(nxt, ka, kb);
        loadV(nxt, va, vb);
      }

      const bool active = (j0 <= i0 + 15) && (j0 + 31 > i0 - 1024);
      if (active) {
        const bf16_t* Kb = Ks + buf * 4096;
        const bf16_t* Vb = Vs + buf * 128 * VROW;
        f32x4 s0 = {}, s1 = {};
        __builtin_amdgcn_s_setprio(1);
#pragma unroll
        for (int kc = 0; kc < 4; ++kc) {
          int col = ((kc * 64 + lc * 16) ^ kxor) >> 1;
          bf16x8 kf0 = *reinterpret_cast<const bf16x8*>(Kb + lr * 128 + col);
          bf16x8 kf1 = *reinterpret_cast<const bf16x8*>(Kb + (16 + lr) * 128 + col);
          s0 = __builtin_amdgcn_mfma_f32_16x16x32_bf16(kf0, qf[kc], s0, 0, 0, 0);
          s1 = __builtin_amdgcn_mfma_f32_16x16x32_bf16(kf1, qf[kc], s1, 0, 0, 0);
        }
        __builtin_amdgcn_s_setprio(0);
        bf16x8 vvf[8];
#pragma unroll
        for (int f = 0; f < 8; ++f)
          vvf[f] = *reinterpret_cast<const bf16x8*>(Vb + (f * 16 + lr) * VROW + lc * 8);

        const bool full = (j0 + 31 <= i0) && (j0 >= i0 - 1008);
        if (!full) {
#pragma unroll
          for (int r = 0; r < 4; ++r) {
            int ja = j0 + lc * 4 + r;
            int jb = ja + 16;
            bool oka = (ja <= qrow) && (ja > qrow - 1024);
            bool okb = (jb <= qrow) && (jb > qrow - 1024);
            s0[r] = oka ? s0[r] : -1e30f;
            s1[r] = okb ? s1[r] : -1e30f;
          }
        }
        float rm = fmaxf(fmaxf(fmaxf(s0[0], s0[1]), fmaxf(s0[2], s0[3])),
                         fmaxf(fmaxf(s1[0], s1[1]), fmaxf(s1[2], s1[3])));

        if (!__all(rm <= mrun + 11.5f)) {
          rm = fmaxf(rm, __shfl_xor(rm, 16));
          rm = fmaxf(rm, __shfl_xor(rm, 32));
          float mnew = fmaxf(mrun, rm);
          float alpha = exp2f(mrun - mnew);
          mrun = mnew;
          lrun *= alpha;
#pragma unroll
          for (int f = 0; f < 8; ++f)
#pragma unroll
            for (int r = 0; r < 4; ++r) o[f][r] *= alpha;
        }

        float p0[4], p1[4], ps = 0.f;
#pragma unroll
        for (int r = 0; r < 4; ++r) {
          p0[r] = exp2f(s0[r] - mrun);
          p1[r] = exp2f(s1[r] - mrun);
          ps += p0[r] + p1[r];
        }
        lrun += ps;

        bf16_t pb[8];
#pragma unroll
        for (int r = 0; r < 4; ++r) {
          pb[r] = __float2bfloat16(p0[r]);
          pb[r + 4] = __float2bfloat16(p1[r]);
        }
        bf16x8 pfrag = *reinterpret_cast<bf16x8*>(pb);

        __builtin_amdgcn_s_setprio(1);
#pragma unroll
        for (int f = 0; f < 8; ++f)
          o[f] = __builtin_amdgcn_mfma_f32_16x16x32_bf16(vvf[f], pfrag, o[f], 0, 0, 0);
        __builtin_amdgcn_s_setprio(0);
      }

      if (do_stage) {
        writeK(buf ^ 1, ka, kb);
        writeV(buf ^ 1, va, vb);
      }
      __syncthreads();
      buf ^= 1;
    }

    float lt = lrun;
    lt += __shfl_xor(lt, 16);
    lt += __shfl_xor(lt, 32);
    float inv = 1.f / lt;
#pragma unroll
    for (int f = 0; f < 8; ++f) {
      bf16_t ob[4];
#pragma unroll
      for (int r = 0; r < 4; ++r) ob[r] = __float2bfloat16(o[f][r] * inv);
      *reinterpret_cast<uint2*>(
          &Y[((size_t)(b * 2048 + qrow)) * 2048 + h * 128 + f * 16 + lc * 4]) =
          *reinterpret_cast<uint2*>(ob);
    }
  }
}

// ---------------- launch ----------------
extern "C" void kernel_launch(void* const* d_in, const int* in_sizes, int n_in,
                              void* d_out, int out_size, void* d_ws, size_t ws_size,
                              hipStream_t stream) {
  const float* x = (const float*)d_in[0];
  const float* cosp = (const float*)d_in[1];
  const float* sinp = (const float*)d_in[2];
  const float* Wa = (const float*)d_in[3];
  const float* Wp = (const float*)d_in[4];
  float* out = (float*)d_out;

  bf16_t* ws = (bf16_t*)d_ws;
  bf16_t* xb = ws;                  // x bf16 -> reused as Q
  bf16_t* wab = ws + 8388608;       // W_attn bf16 -> reused as K,V
  bf16_t* wpb = ws + 14680064;      // W_proj bf16
  bf16_t* qkv = ws + 18874368;      // qkv bf16 -> reused as Y,Vt
  bf16_t* Q = xb;                   // [B][H][T][HS]
  bf16_t* Kr = wab;                 // [B][G][T][HS]
  bf16_t* V = wab + 2097152;        // [B][G][T][HS]
  bf16_t* Y = qkv;                  // [B][T][H][HS]
  bf16_t* Vt = qkv + 8388608;       // [B][G][HS][T]

  cvt_f32_to_bf16<<<4096, 256, 0, stream>>>(x, xb, 1048576);
  cvt_f32_to_bf16<<<3072, 256, 0, stream>>>(Wa, wab, 786432);
  cvt_f32_to_bf16<<<2048, 256, 0, stream>>>(Wp, wpb, 524288);

  // qkv = xb @ wab^T : M=4096 N=3072 K=2048  (192 blocks, 1/CU)
  gemm256<bf16_t><<<dim3(12, 16), 512, 0, stream>>>(xb, wab, qkv, 4096, 3072, 2048);

  rope_scatter<<<4096, 256, 0, stream>>>(qkv, cosp, sinp, Q, Kr, V);

  transpose_v<<<dim3(64, 4, 8), dim3(32, 8), 0, stream>>>(V, Vt);

  attn_swa<<<dim3(24, 16, 2), 256, 0, stream>>>(Q, Kr, Vt, Y);

  // out = Y @ wpb^T : M=4096 N=2048 K=2048  (128 blocks, 1/CU)
  gemm256<float><<<dim3(8, 16), 512, 0, stream>>>(Y, wpb, out, 4096, 2048, 2048);
}

// Round 12
// 226.102 us; speedup vs baseline: 1.2087x; 1.0916x over previous
//
#include <hip/hip_runtime.h>
#include <hip/hip_bf16.h>
#include <cstdint>
#include <type_traits>

using bf16_t = __hip_bfloat16;
typedef __bf16 bf16x8 __attribute__((ext_vector_type(8)));
typedef float f32x4 __attribute__((ext_vector_type(4)));

typedef __attribute__((address_space(3))) uint32_t lds_u32_t;
typedef const __attribute__((address_space(1))) uint32_t glb_u32_t;

// ---------------- f32 -> bf16 convert, 8 elems/thread ----------------
__global__ void cvt_f32_to_bf16(const float* __restrict__ in, bf16_t* __restrict__ out, int n8) {
  int stride = gridDim.x * blockDim.x;
  for (int i = blockIdx.x * blockDim.x + threadIdx.x; i < n8; i += stride) {
    const float4* p = reinterpret_cast<const float4*>(in) + (size_t)i * 2;
    float4 a = p[0];
    float4 b = p[1];
    bf16_t o[8];
    o[0] = __float2bfloat16(a.x); o[1] = __float2bfloat16(a.y);
    o[2] = __float2bfloat16(a.z); o[3] = __float2bfloat16(a.w);
    o[4] = __float2bfloat16(b.x); o[5] = __float2bfloat16(b.y);
    o[6] = __float2bfloat16(b.z); o[7] = __float2bfloat16(b.w);
    *reinterpret_cast<uint4*>(out + (size_t)i * 8) = *reinterpret_cast<const uint4*>(o);
  }
}

// ---------------- bf16 GEMM, 256xBN tile, 4-phase schedule ---------------
// C[M,N] = A[M,K] * Bt[N,K]^T.  512 thr = 8 waves (2M x 4N), per-wave
// 128 x BN/4 output (acc[8][BN/64] f32x4), BK=64, LDS double-buffered.
// BN chosen per call site so grid == 256 blocks == 1/CU exactly.
// T2 swizzle (pre-swizzled source + swizzled ds_read), T3/T4 4-phase with
// stages issued phases 0-1 and one drain at tile boundary, T5 setprio,
// T1 bijective XCD swizzle (nwg % 8 == 0).
template <int BN, typename OutT>
__global__ __launch_bounds__(512, 2) void gemm256(const bf16_t* __restrict__ A,
                                                  const bf16_t* __restrict__ Bt,
                                                  OutT* __restrict__ C,
                                                  int M, int N, int K) {
  constexpr int JN = BN / 64;        // B j-fragments per wave
  constexpr int JLO = (JN + 1) / 2;  // phase split
  constexpr int BL = BN / 64;        // B staging loads per thread
  __shared__ __align__(16) bf16_t As[2 * 256 * 64];
  __shared__ __align__(16) bf16_t Bs[2 * BN * 64];
  const int tid = threadIdx.x;
  const int lane = tid & 63;
  const int w = tid >> 6;          // 0..7
  const int wm = w >> 2, wn = w & 3;
  const int lr = lane & 15, lc = lane >> 4;

  // T1: XCD-aware bijective block swizzle (requires nwg % 8 == 0)
  const int nwg = gridDim.x * gridDim.y;
  const int orig = blockIdx.y * gridDim.x + blockIdx.x;
  const int cpx = nwg >> 3;
  const int swz = (orig & 7) * cpx + (orig >> 3);
  const int bx = swz % gridDim.x, by = swz / gridDim.x;
  const int m0 = by * 256, n0 = bx * BN;

  // staging: chunk c = l*512 + tid covers LDS row c>>3 (= l*64 + tid>>3),
  // phys 16B slot c&7; source col pre-swizzled so linear dest == swizzled.
  const int srow = tid >> 3;                       // 0..63
  const int scol = ((tid & 7) ^ (srow & 7)) * 8;   // elems
  const bf16_t* Asrc = A + (size_t)(m0 + srow) * K + scol;
  const bf16_t* Bsrc = Bt + (size_t)(n0 + srow) * K + scol;

  f32x4 acc[8][JN] = {};

  auto stageA = [&](int bufi, int kt) {
#pragma unroll
    for (int l = 0; l < 4; ++l)
      __builtin_amdgcn_global_load_lds(
          (glb_u32_t*)(Asrc + (size_t)kt * 64 + (size_t)l * 64 * K),
          (lds_u32_t*)(As + bufi * 16384 + l * 4096 + w * 512), 16, 0, 0);
  };
  auto stageB = [&](int bufi, int kt) {
#pragma unroll
    for (int l = 0; l < BL; ++l)
      __builtin_amdgcn_global_load_lds(
          (glb_u32_t*)(Bsrc + (size_t)kt * 64 + (size_t)l * 64 * K),
          (lds_u32_t*)(Bs + bufi * BN * 64 + l * 4096 + w * 512), 16, 0, 0);
  };

  const int nt = K >> 6;
  // prologue: stage K-tile 0 into buf 0
  stageA(0, 0);
  stageB(0, 0);
  asm volatile("s_waitcnt vmcnt(0)" ::: "memory");
  __builtin_amdgcn_s_barrier();

  bf16x8 a[4][2], bb[JN][2];
  for (int t = 0; t < nt; ++t) {
    const int buf = t & 1;
    const char* Ab = (const char*)(As + buf * 16384);
    const char* Bb = (const char*)(Bs + buf * BN * 64);
    const bool st = (t + 1 < nt);

    auto rdA = [&](int i, int kk) {
      int R = wm * 128 + i * 16 + lr;
      return *reinterpret_cast<const bf16x8*>(
          Ab + R * 128 + ((kk * 64 + lc * 16) ^ ((R & 7) << 4)));
    };
    auto rdB = [&](int j, int kk) {
      int R = wn * (BN / 4) + j * 16 + lr;
      return *reinterpret_cast<const bf16x8*>(
          Bb + R * 128 + ((kk * 64 + lc * 16) ^ ((R & 7) << 4)));
    };

    // ---- phase 0: read A(i0-3) + B(jlo); stage A(t+1); mfma i0-3 x jlo
#pragma unroll
    for (int i = 0; i < 4; ++i) { a[i][0] = rdA(i, 0); a[i][1] = rdA(i, 1); }
#pragma unroll
    for (int j = 0; j < JLO; ++j) { bb[j][0] = rdB(j, 0); bb[j][1] = rdB(j, 1); }
    if (st) stageA(buf ^ 1, t + 1);
    asm volatile("" ::: "memory");
    __builtin_amdgcn_s_barrier();
    __builtin_amdgcn_s_setprio(1);
#pragma unroll
    for (int i = 0; i < 4; ++i)
#pragma unroll
      for (int j = 0; j < JLO; ++j) {
        acc[i][j] = __builtin_amdgcn_mfma_f32_16x16x32_bf16(a[i][0], bb[j][0], acc[i][j], 0, 0, 0);
        acc[i][j] = __builtin_amdgcn_mfma_f32_16x16x32_bf16(a[i][1], bb[j][1], acc[i][j], 0, 0, 0);
      }
    __builtin_amdgcn_s_setprio(0);
    asm volatile("" ::: "memory");
    __builtin_amdgcn_s_barrier();

    // ---- phase 1: read B(jhi); stage B(t+1); mfma i0-3 x jhi
#pragma unroll
    for (int j = JLO; j < JN; ++j) { bb[j][0] = rdB(j, 0); bb[j][1] = rdB(j, 1); }
    if (st) stageB(buf ^ 1, t + 1);
    asm volatile("" ::: "memory");
    __builtin_amdgcn_s_barrier();
    __builtin_amdgcn_s_setprio(1);
#pragma unroll
    for (int i = 0; i < 4; ++i)
#pragma unroll
      for (int j = JLO; j < JN; ++j) {
        acc[i][j] = __builtin_amdgcn_mfma_f32_16x16x32_bf16(a[i][0], bb[j][0], acc[i][j], 0, 0, 0);
        acc[i][j] = __builtin_amdgcn_mfma_f32_16x16x32_bf16(a[i][1], bb[j][1], acc[i][j], 0, 0, 0);
      }
    __builtin_amdgcn_s_setprio(0);
    asm volatile("" ::: "memory");
    __builtin_amdgcn_s_barrier();

    // ---- phase 2: read A(i4-7) (overwrite a[]); mfma i4-7 x jhi
#pragma unroll
    for (int i = 0; i < 4; ++i) { a[i][0] = rdA(i + 4, 0); a[i][1] = rdA(i + 4, 1); }
    asm volatile("" ::: "memory");
    __builtin_amdgcn_s_barrier();
    __builtin_amdgcn_s_setprio(1);
#pragma unroll
    for (int i = 0; i < 4; ++i)
#pragma unroll
      for (int j = JLO; j < JN; ++j) {
        acc[i + 4][j] = __builtin_amdgcn_mfma_f32_16x16x32_bf16(a[i][0], bb[j][0], acc[i + 4][j], 0, 0, 0);
        acc[i + 4][j] = __builtin_amdgcn_mfma_f32_16x16x32_bf16(a[i][1], bb[j][1], acc[i + 4][j], 0, 0, 0);
      }
    __builtin_amdgcn_s_setprio(0);
    asm volatile("" ::: "memory");
    __builtin_amdgcn_s_barrier();

    // ---- phase 3: mfma i4-7 x jlo (all operands resident)
    __builtin_amdgcn_s_setprio(1);
#pragma unroll
    for (int i = 0; i < 4; ++i)
#pragma unroll
      for (int j = 0; j < JLO; ++j) {
        acc[i + 4][j] = __builtin_amdgcn_mfma_f32_16x16x32_bf16(a[i][0], bb[j][0], acc[i + 4][j], 0, 0, 0);
        acc[i + 4][j] = __builtin_amdgcn_mfma_f32_16x16x32_bf16(a[i][1], bb[j][1], acc[i + 4][j], 0, 0, 0);
      }
    __builtin_amdgcn_s_setprio(0);

    // ---- tile boundary: staged tile (issued phases 0-1, ~2 phases of
    // cover) must have landed; own ds_reads already consumed.
    asm volatile("s_waitcnt lgkmcnt(0)" ::: "memory");
    asm volatile("s_waitcnt vmcnt(0)" ::: "memory");
    __builtin_amdgcn_s_barrier();
  }

  // epilogue: C/D layout col=lane&15, row=(lane>>4)*4+reg  [m89/m91]
#pragma unroll
  for (int i = 0; i < 8; ++i)
#pragma unroll
    for (int j = 0; j < JN; ++j) {
      int row = m0 + wm * 128 + i * 16 + lc * 4;
      int col = n0 + wn * (BN / 4) + j * 16 + lr;
#pragma unroll
      for (int r = 0; r < 4; ++r) {
        float v = acc[i][j][r];
        if constexpr (std::is_same<OutT, float>::value)
          C[(size_t)(row + r) * N + col] = v;
        else
          C[(size_t)(row + r) * N + col] = __float2bfloat16(v);
      }
    }
}

// ---------------- RoPE + scatter qkv -> Q (scaled), K, V ----------------
__global__ __launch_bounds__(256) void rope_scatter(const bf16_t* __restrict__ qkv,
                                                    const float* __restrict__ cosp,
                                                    const float* __restrict__ sinp,
                                                    bf16_t* __restrict__ Q,
                                                    bf16_t* __restrict__ K,
                                                    bf16_t* __restrict__ V) {
  const int row = blockIdx.x;  // b*2048 + t
  const int b = row >> 11, t = row & 2047;
  const bf16_t* src = qkv + (size_t)row * 3072;
  for (int n = threadIdx.x; n < 3072; n += 256) {
    int g = n / 768;
    int r = n - g * 768;
    int slot = r >> 7;
    int d = r & 127;
    if (slot == 5) {
      V[(((size_t)(b * 4 + g)) * 2048 + t) * 128 + d] = src[n];
    } else {
      float v = __bfloat162float(src[n]);
      float other = __bfloat162float(src[n ^ 64]);
      float c = cosp[t * 128 + d];
      float s = sinp[t * 128 + d];
      float rot = (d < 64) ? -other : other;
      float res = v * c + rot * s;
      if (slot < 4) {
        int h = g * 4 + slot;
        // fold softmax scale 1/sqrt(128) AND log2(e) into Q (attn uses exp2)
        Q[(((size_t)(b * 16 + h)) * 2048 + t) * 128 + d] =
            __float2bfloat16(res * (0.08838834764831843f * 1.4426950408889634f));
      } else {
        K[(((size_t)(b * 4 + g)) * 2048 + t) * 128 + d] = __float2bfloat16(res);
      }
    }
  }
}

// ---------------- V [bg][t][d] -> Vt [bg][d][t] ----------------
__global__ void transpose_v(const bf16_t* __restrict__ V, bf16_t* __restrict__ Vt) {
  __shared__ bf16_t tile[32][33];
  const int bg = blockIdx.z;
  const int t0 = blockIdx.x * 32;
  const int d0 = blockIdx.y * 32;
  const bf16_t* src = V + (size_t)bg * 2048 * 128;
  bf16_t* dst = Vt + (size_t)bg * 128 * 2048;
#pragma unroll
  for (int i = threadIdx.y; i < 32; i += 8)
    tile[i][threadIdx.x] = src[(size_t)(t0 + i) * 128 + d0 + threadIdx.x];
  __syncthreads();
#pragma unroll
  for (int i = threadIdx.y; i < 32; i += 8)
    dst[(size_t)(d0 + i) * 2048 + t0 + threadIdx.x] = tile[threadIdx.x][i];
}

// ---------------- sliding-window flash attention (v10, plateau) ----------
#define VROW 40
__global__ __launch_bounds__(256) void attn_swa(const bf16_t* __restrict__ Q,
                                                const bf16_t* __restrict__ K,
                                                const bf16_t* __restrict__ Vt,
                                                bf16_t* __restrict__ Y) {
  __shared__ __align__(16) bf16_t Ks[2 * 32 * 128];
  __shared__ __align__(16) bf16_t Vs[2 * 128 * VROW];

  const int tid = threadIdx.x;
  const int lane = tid & 63;
  const int w = tid >> 6;
  const int lr = lane & 15, lc = lane >> 4;
  const int b = blockIdx.z, h = blockIdx.y;
  const int g = h >> 2;

  // segment list: blockIdx.x<16 -> heavy tile x+16; else light pair (p,15-p)
  int nseg, sx0, sx1 = 0;
  if (blockIdx.x < 16) {
    nseg = 1;
    sx0 = blockIdx.x + 16;
  } else {
    nseg = 2;
    sx0 = blockIdx.x - 16;
    sx1 = 15 - sx0;
  }

  const bf16_t* Qp = Q + ((size_t)(b * 16 + h) * 2048) * 128;
  const bf16_t* Kp = K + ((size_t)(b * 4 + g) * 2048) * 128;
  const bf16_t* Vp = Vt + ((size_t)(b * 4 + g) * 128) * 2048;

  const int kmj = tid >> 4;
  const int kmc = ((tid & 15) ^ (kmj & 7)) * 8;
  const bf16_t* Ksrc = Kp + (size_t)kmj * 128 + kmc;
  const int vd = tid >> 2, vc = tid & 3;
  const bf16_t* Vsrc = Vp + (size_t)vd * 2048 + vc * 8;
  const int vdst = vd * VROW + (vc & 1) * 16 + (vc >> 1) * 4;

  auto loadK = [&](int j0, uint4& ka, uint4& kb) {
    const bf16_t* s = Ksrc + (size_t)j0 * 128;
    ka = *reinterpret_cast<const uint4*>(s);
    kb = *reinterpret_cast<const uint4*>(s + 16 * 128);
  };
  auto writeK = [&](int bufi, uint4 ka, uint4 kb) {
    *reinterpret_cast<uint4*>(Ks + bufi * 4096 + tid * 8) = ka;
    *reinterpret_cast<uint4*>(Ks + bufi * 4096 + 2048 + tid * 8) = kb;
  };
  auto loadV = [&](int j0, uint4& a, uint4& bqv) {
    a = *reinterpret_cast<const uint4*>(Vsrc + j0);
    bqv = *reinterpret_cast<const uint4*>(Vsrc + 64 * 2048 + j0);
  };
  auto writeV = [&](int bufi, uint4 a, uint4 bqv) {
    bf16_t* p = Vs + bufi * 128 * VROW + vdst;
    *reinterpret_cast<uint2*>(p) = make_uint2(a.x, a.y);
    *reinterpret_cast<uint2*>(p + 8) = make_uint2(a.z, a.w);
    bf16_t* p1 = p + 64 * VROW;
    *reinterpret_cast<uint2*>(p1) = make_uint2(bqv.x, bqv.y);
    *reinterpret_cast<uint2*>(p1 + 8) = make_uint2(bqv.z, bqv.w);
  };

  const int kxor = (lr & 7) << 4;

  for (int sidx = 0; sidx < nseg; ++sidx) {
    const int i0b = ((sidx == 0) ? sx0 : sx1) * 64;
    const int i0 = i0b + w * 16;
    const int qrow = i0 + lr;

    bf16x8 qf[4];
#pragma unroll
    for (int kc = 0; kc < 4; ++kc)
      qf[kc] = *reinterpret_cast<const bf16x8*>(&Qp[(size_t)qrow * 128 + kc * 32 + lc * 8]);

    f32x4 o[8] = {};
    float mrun = -1e30f, lrun = 0.f;  // lrun LANE-PARTIAL (reduced at epilogue)

    int lo = i0b - 1023;
    if (lo < 0) lo = 0;
    const int jstart = lo & ~31;
    const int jlast = i0b + 32;

    {
      uint4 ka, kb, va, vb;
      loadK(jstart, ka, kb);
      loadV(jstart, va, vb);
      writeK(0, ka, kb);
      writeV(0, va, vb);
    }
    __syncthreads();

    int buf = 0;
    for (int j0 = jstart; j0 <= jlast; j0 += 32) {
      const int nxt = j0 + 32;
      uint4 ka, kb, va, vb;
      const bool do_stage = (nxt <= jlast);
      if (do_stage) {
        loadK(nxt, ka, kb);
        loadV(nxt, va, vb);
      }

      const bool active = (j0 <= i0 + 15) && (j0 + 31 > i0 - 1024);
      if (active) {
        const bf16_t* Kb = Ks + buf * 4096;
        const bf16_t* Vb = Vs + buf * 128 * VROW;
        f32x4 s0 = {}, s1 = {};
        __builtin_amdgcn_s_setprio(1);
#pragma unroll
        for (int kc = 0; kc < 4; ++kc) {
          int col = ((kc * 64 + lc * 16) ^ kxor) >> 1;
          bf16x8 kf0 = *reinterpret_cast<const bf16x8*>(Kb + lr * 128 + col);
          bf16x8 kf1 = *reinterpret_cast<const bf16x8*>(Kb + (16 + lr) * 128 + col);
          s0 = __builtin_amdgcn_mfma_f32_16x16x32_bf16(kf0, qf[kc], s0, 0, 0, 0);
          s1 = __builtin_amdgcn_mfma_f32_16x16x32_bf16(kf1, qf[kc], s1, 0, 0, 0);
        }
        __builtin_amdgcn_s_setprio(0);
        bf16x8 vvf[8];
#pragma unroll
        for (int f = 0; f < 8; ++f)
          vvf[f] = *reinterpret_cast<const bf16x8*>(Vb + (f * 16 + lr) * VROW + lc * 8);

        const bool full = (j0 + 31 <= i0) && (j0 >= i0 - 1008);
        if (!full) {
#pragma unroll
          for (int r = 0; r < 4; ++r) {
            int ja = j0 + lc * 4 + r;
            int jb = ja + 16;
            bool oka = (ja <= qrow) && (ja > qrow - 1024);
            bool okb = (jb <= qrow) && (jb > qrow - 1024);
            s0[r] = oka ? s0[r] : -1e30f;
            s1[r] = okb ? s1[r] : -1e30f;
          }
        }
        float rm = fmaxf(fmaxf(fmaxf(s0[0], s0[1]), fmaxf(s0[2], s0[3])),
                         fmaxf(fmaxf(s1[0], s1[1]), fmaxf(s1[2], s1[3])));

        if (!__all(rm <= mrun + 11.5f)) {
          rm = fmaxf(rm, __shfl_xor(rm, 16));
          rm = fmaxf(rm, __shfl_xor(rm, 32));
          float mnew = fmaxf(mrun, rm);
          float alpha = exp2f(mrun - mnew);
          mrun = mnew;
          lrun *= alpha;
#pragma unroll
          for (int f = 0; f < 8; ++f)
#pragma unroll
            for (int r = 0; r < 4; ++r) o[f][r] *= alpha;
        }

        float p0[4], p1[4], ps = 0.f;
#pragma unroll
        for (int r = 0; r < 4; ++r) {
          p0[r] = exp2f(s0[r] - mrun);
          p1[r] = exp2f(s1[r] - mrun);
          ps += p0[r] + p1[r];
        }
        lrun += ps;

        bf16_t pb[8];
#pragma unroll
        for (int r = 0; r < 4; ++r) {
          pb[r] = __float2bfloat16(p0[r]);
          pb[r + 4] = __float2bfloat16(p1[r]);
        }
        bf16x8 pfrag = *reinterpret_cast<bf16x8*>(pb);

        __builtin_amdgcn_s_setprio(1);
#pragma unroll
        for (int f = 0; f < 8; ++f)
          o[f] = __builtin_amdgcn_mfma_f32_16x16x32_bf16(vvf[f], pfrag, o[f], 0, 0, 0);
        __builtin_amdgcn_s_setprio(0);
      }

      if (do_stage) {
        writeK(buf ^ 1, ka, kb);
        writeV(buf ^ 1, va, vb);
      }
      __syncthreads();
      buf ^= 1;
    }

    float lt = lrun;
    lt += __shfl_xor(lt, 16);
    lt += __shfl_xor(lt, 32);
    float inv = 1.f / lt;
#pragma unroll
    for (int f = 0; f < 8; ++f) {
      bf16_t ob[4];
#pragma unroll
      for (int r = 0; r < 4; ++r) ob[r] = __float2bfloat16(o[f][r] * inv);
      *reinterpret_cast<uint2*>(
          &Y[((size_t)(b * 2048 + qrow)) * 2048 + h * 128 + f * 16 + lc * 4]) =
          *reinterpret_cast<uint2*>(ob);
    }
  }
}

// ---------------- launch ----------------
extern "C" void kernel_launch(void* const* d_in, const int* in_sizes, int n_in,
                              void* d_out, int out_size, void* d_ws, size_t ws_size,
                              hipStream_t stream) {
  const float* x = (const float*)d_in[0];
  const float* cosp = (const float*)d_in[1];
  const float* sinp = (const float*)d_in[2];
  const float* Wa = (const float*)d_in[3];
  const float* Wp = (const float*)d_in[4];
  float* out = (float*)d_out;

  bf16_t* ws = (bf16_t*)d_ws;
  bf16_t* xb = ws;                  // x bf16 -> reused as Q
  bf16_t* wab = ws + 8388608;       // W_attn bf16 -> reused as K,V
  bf16_t* wpb = ws + 14680064;      // W_proj bf16
  bf16_t* qkv = ws + 18874368;      // qkv bf16 -> reused as Y,Vt
  bf16_t* Q = xb;                   // [B][H][T][HS]
  bf16_t* Kr = wab;                 // [B][G][T][HS]
  bf16_t* V = wab + 2097152;        // [B][G][T][HS]
  bf16_t* Y = qkv;                  // [B][T][H][HS]
  bf16_t* Vt = qkv + 8388608;       // [B][G][HS][T]

  cvt_f32_to_bf16<<<4096, 256, 0, stream>>>(x, xb, 1048576);
  cvt_f32_to_bf16<<<3072, 256, 0, stream>>>(Wa, wab, 786432);
  cvt_f32_to_bf16<<<2048, 256, 0, stream>>>(Wp, wpb, 524288);

  // qkv = xb @ wab^T : M=4096 N=3072 K=2048  (BN=192 -> 16x16 = 256 blocks)
  gemm256<192, bf16_t><<<dim3(16, 16), 512, 0, stream>>>(xb, wab, qkv, 4096, 3072, 2048);

  rope_scatter<<<4096, 256, 0, stream>>>(qkv, cosp, sinp, Q, Kr, V);

  transpose_v<<<dim3(64, 4, 8), dim3(32, 8), 0, stream>>>(V, Vt);

  attn_swa<<<dim3(24, 16, 2), 256, 0, stream>>>(Q, Kr, Vt, Y);

  // out = Y @ wpb^T : M=4096 N=2048 K=2048  (BN=128 -> 16x16 = 256 blocks)
  gemm256<128, float><<<dim3(16, 16), 512, 0, stream>>>(Y, wpb, out, 4096, 2048, 2048);
}

// Round 13
// 212.766 us; speedup vs baseline: 1.2845x; 1.0627x over previous
//
#include <hip/hip_runtime.h>
#include <hip/hip_bf16.h>
#include <cstdint>
#include <type_traits>

using bf16_t = __hip_bfloat16;
typedef __bf16 bf16x8 __attribute__((ext_vector_type(8)));
typedef float f32x4 __attribute__((ext_vector_type(4)));

typedef __attribute__((address_space(3))) uint32_t lds_u32_t;
typedef const __attribute__((address_space(1))) uint32_t glb_u32_t;

// ---------------- f32 -> bf16 convert, 8 elems/thread ----------------
__global__ void cvt_f32_to_bf16(const float* __restrict__ in, bf16_t* __restrict__ out, int n8) {
  int stride = gridDim.x * blockDim.x;
  for (int i = blockIdx.x * blockDim.x + threadIdx.x; i < n8; i += stride) {
    const float4* p = reinterpret_cast<const float4*>(in) + (size_t)i * 2;
    float4 a = p[0];
    float4 b = p[1];
    bf16_t o[8];
    o[0] = __float2bfloat16(a.x); o[1] = __float2bfloat16(a.y);
    o[2] = __float2bfloat16(a.z); o[3] = __float2bfloat16(a.w);
    o[4] = __float2bfloat16(b.x); o[5] = __float2bfloat16(b.y);
    o[6] = __float2bfloat16(b.z); o[7] = __float2bfloat16(b.w);
    *reinterpret_cast<uint4*>(out + (size_t)i * 8) = *reinterpret_cast<const uint4*>(o);
  }
}

// ---------------- bf16 GEMM, 256xBN tile, counted-vmcnt pipeline ---------
// C[M,N] = A[M,K] * Bt[N,K]^T.  512 thr = 8 waves (2M x 4N), per-wave
// 128 x BN/4 output, BK=64, LDS double-buffered. Grid = 256 blocks = 1/CU.
// T4 proper: per tile two phases with 1-TILE-LAG counted waits --
//   phase A: vmcnt(BL) [own A(t), staged a full tile ago -> free] ->
//            barrier -> ds_read all A frags -> issue stage A(t+1)
//   phase B: vmcnt(4)  [own B(t); A(t+1) stays IN FLIGHT across barriers]
//            -> barrier -> ds_read B frags -> issue stage B(t+1) ->
//            setprio(1) -> 24*JN MFMA -> setprio(0)
// Never vmcnt(0) in the main loop (except the final tile, no prefetch).
// Safety: counted wait (own chunks) + barrier => region landed for all
// waves; stage X(t+1) overwrites X(t-1) whose reads drained before the
// previous barrier. FIFO issue order A-then-B each tile.
// T2 swizzle (pre-swizzled source + swizzled ds_read), T1 XCD swizzle.
template <int BN, typename OutT>
__global__ __launch_bounds__(512, 2) void gemm256(const bf16_t* __restrict__ A,
                                                  const bf16_t* __restrict__ Bt,
                                                  OutT* __restrict__ C,
                                                  int M, int N, int K) {
  constexpr int JN = BN / 64;        // B j-fragments per wave
  constexpr int BL = BN / 64;        // B staging loads per thread
  __shared__ __align__(16) bf16_t As[2 * 256 * 64];
  __shared__ __align__(16) bf16_t Bs[2 * BN * 64];
  const int tid = threadIdx.x;
  const int lane = tid & 63;
  const int w = tid >> 6;          // 0..7
  const int wm = w >> 2, wn = w & 3;
  const int lr = lane & 15, lc = lane >> 4;

  // T1: XCD-aware bijective block swizzle (requires nwg % 8 == 0)
  const int nwg = gridDim.x * gridDim.y;
  const int orig = blockIdx.y * gridDim.x + blockIdx.x;
  const int cpx = nwg >> 3;
  const int swz = (orig & 7) * cpx + (orig >> 3);
  const int bx = swz % gridDim.x, by = swz / gridDim.x;
  const int m0 = by * 256, n0 = bx * BN;

  // staging: chunk c = l*512 + tid covers LDS row l*64 + (tid>>3), phys 16B
  // slot tid&7; source col pre-swizzled so linear dest == swizzled layout.
  const int srow = tid >> 3;                       // 0..63
  const int scol = ((tid & 7) ^ (srow & 7)) * 8;   // elems
  const bf16_t* Asrc = A + (size_t)(m0 + srow) * K + scol;
  const bf16_t* Bsrc = Bt + (size_t)(n0 + srow) * K + scol;

  f32x4 acc[8][JN] = {};

  auto stageA = [&](int bufi, int kt) {
#pragma unroll
    for (int l = 0; l < 4; ++l)
      __builtin_amdgcn_global_load_lds(
          (glb_u32_t*)(Asrc + (size_t)kt * 64 + (size_t)l * 64 * K),
          (lds_u32_t*)(As + bufi * 16384 + l * 4096 + w * 512), 16, 0, 0);
  };
  auto stageB = [&](int bufi, int kt) {
#pragma unroll
    for (int l = 0; l < BL; ++l)
      __builtin_amdgcn_global_load_lds(
          (glb_u32_t*)(Bsrc + (size_t)kt * 64 + (size_t)l * 64 * K),
          (lds_u32_t*)(Bs + bufi * BN * 64 + l * 4096 + w * 512), 16, 0, 0);
  };

  const int nt = K >> 6;
  // prologue: stage tile 0 (A first, then B -- FIFO order matters)
  stageA(0, 0);
  stageB(0, 0);

  bf16x8 a[8][2], bb[JN][2];
  for (int t = 0; t < nt; ++t) {
    const int buf = t & 1;
    const char* Ab = (const char*)(As + buf * 16384);
    const char* Bb = (const char*)(Bs + buf * BN * 64);
    const bool st = (t + 1 < nt);

    auto rdA = [&](int i, int kk) {
      int R = wm * 128 + i * 16 + lr;
      return *reinterpret_cast<const bf16x8*>(
          Ab + R * 128 + ((kk * 64 + lc * 16) ^ ((R & 7) << 4)));
    };
    auto rdB = [&](int j, int kk) {
      int R = wn * (BN / 4) + j * 16 + lr;
      return *reinterpret_cast<const bf16x8*>(
          Bb + R * 128 + ((kk * 64 + lc * 16) ^ ((R & 7) << 4)));
    };

    // ---- phase A: own A(t) landed (issued a full tile ago); B(t) and
    // (later) A(t+1) remain in flight.
    if constexpr (BL == 3) {
      asm volatile("s_waitcnt vmcnt(3)" ::: "memory");
    } else {
      asm volatile("s_waitcnt vmcnt(2)" ::: "memory");
    }
    __builtin_amdgcn_s_barrier();  // all waves' A(t) DMA chunks landed
#pragma unroll
    for (int i = 0; i < 8; ++i) { a[i][0] = rdA(i, 0); a[i][1] = rdA(i, 1); }
    if (st) stageA(buf ^ 1, t + 1);

    // ---- phase B: own B(t) landed; A(t+1) stays in flight (count 4).
    if (st) {
      asm volatile("s_waitcnt vmcnt(4)" ::: "memory");
    } else {
      asm volatile("s_waitcnt vmcnt(0)" ::: "memory");
    }
    __builtin_amdgcn_s_barrier();  // all waves' B(t) landed
#pragma unroll
    for (int j = 0; j < JN; ++j) { bb[j][0] = rdB(j, 0); bb[j][1] = rdB(j, 1); }
    if (st) stageB(buf ^ 1, t + 1);

    __builtin_amdgcn_s_setprio(1);
#pragma unroll
    for (int i = 0; i < 8; ++i)
#pragma unroll
      for (int j = 0; j < JN; ++j) {
        acc[i][j] = __builtin_amdgcn_mfma_f32_16x16x32_bf16(a[i][0], bb[j][0], acc[i][j], 0, 0, 0);
        acc[i][j] = __builtin_amdgcn_mfma_f32_16x16x32_bf16(a[i][1], bb[j][1], acc[i][j], 0, 0, 0);
      }
    __builtin_amdgcn_s_setprio(0);
  }

  // epilogue: C/D layout col=lane&15, row=(lane>>4)*4+reg  [m89/m91]
#pragma unroll
  for (int i = 0; i < 8; ++i)
#pragma unroll
    for (int j = 0; j < JN; ++j) {
      int row = m0 + wm * 128 + i * 16 + lc * 4;
      int col = n0 + wn * (BN / 4) + j * 16 + lr;
#pragma unroll
      for (int r = 0; r < 4; ++r) {
        float v = acc[i][j][r];
        if constexpr (std::is_same<OutT, float>::value)
          C[(size_t)(row + r) * N + col] = v;
        else
          C[(size_t)(row + r) * N + col] = __float2bfloat16(v);
      }
    }
}

// ---------------- RoPE + scatter qkv -> Q (scaled), K, V ----------------
__global__ __launch_bounds__(256) void rope_scatter(const bf16_t* __restrict__ qkv,
                                                    const float* __restrict__ cosp,
                                                    const float* __restrict__ sinp,
                                                    bf16_t* __restrict__ Q,
                                                    bf16_t* __restrict__ K,
                                                    bf16_t* __restrict__ V) {
  const int row = blockIdx.x;  // b*2048 + t
  const int b = row >> 11, t = row & 2047;
  const bf16_t* src = qkv + (size_t)row * 3072;
  for (int n = threadIdx.x; n < 3072; n += 256) {
    int g = n / 768;
    int r = n - g * 768;
    int slot = r >> 7;
    int d = r & 127;
    if (slot == 5) {
      V[(((size_t)(b * 4 + g)) * 2048 + t) * 128 + d] = src[n];
    } else {
      float v = __bfloat162float(src[n]);
      float other = __bfloat162float(src[n ^ 64]);
      float c = cosp[t * 128 + d];
      float s = sinp[t * 128 + d];
      float rot = (d < 64) ? -other : other;
      float res = v * c + rot * s;
      if (slot < 4) {
        int h = g * 4 + slot;
        // fold softmax scale 1/sqrt(128) AND log2(e) into Q (attn uses exp2)
        Q[(((size_t)(b * 16 + h)) * 2048 + t) * 128 + d] =
            __float2bfloat16(res * (0.08838834764831843f * 1.4426950408889634f));
      } else {
        K[(((size_t)(b * 4 + g)) * 2048 + t) * 128 + d] = __float2bfloat16(res);
      }
    }
  }
}

// ---------------- V [bg][t][d] -> Vt [bg][d][t] ----------------
__global__ void transpose_v(const bf16_t* __restrict__ V, bf16_t* __restrict__ Vt) {
  __shared__ bf16_t tile[32][33];
  const int bg = blockIdx.z;
  const int t0 = blockIdx.x * 32;
  const int d0 = blockIdx.y * 32;
  const bf16_t* src = V + (size_t)bg * 2048 * 128;
  bf16_t* dst = Vt + (size_t)bg * 128 * 2048;
#pragma unroll
  for (int i = threadIdx.y; i < 32; i += 8)
    tile[i][threadIdx.x] = src[(size_t)(t0 + i) * 128 + d0 + threadIdx.x];
  __syncthreads();
#pragma unroll
  for (int i = threadIdx.y; i < 32; i += 8)
    dst[(size_t)(d0 + i) * 2048 + t0 + threadIdx.x] = tile[threadIdx.x][i];
}

// ---------------- sliding-window flash attention (v10, plateau) ----------
#define VROW 40
__global__ __launch_bounds__(256) void attn_swa(const bf16_t* __restrict__ Q,
                                                const bf16_t* __restrict__ K,
                                                const bf16_t* __restrict__ Vt,
                                                bf16_t* __restrict__ Y) {
  __shared__ __align__(16) bf16_t Ks[2 * 32 * 128];
  __shared__ __align__(16) bf16_t Vs[2 * 128 * VROW];

  const int tid = threadIdx.x;
  const int lane = tid & 63;
  const int w = tid >> 6;
  const int lr = lane & 15, lc = lane >> 4;
  const int b = blockIdx.z, h = blockIdx.y;
  const int g = h >> 2;

  // segment list: blockIdx.x<16 -> heavy tile x+16; else light pair (p,15-p)
  int nseg, sx0, sx1 = 0;
  if (blockIdx.x < 16) {
    nseg = 1;
    sx0 = blockIdx.x + 16;
  } else {
    nseg = 2;
    sx0 = blockIdx.x - 16;
    sx1 = 15 - sx0;
  }

  const bf16_t* Qp = Q + ((size_t)(b * 16 + h) * 2048) * 128;
  const bf16_t* Kp = K + ((size_t)(b * 4 + g) * 2048) * 128;
  const bf16_t* Vp = Vt + ((size_t)(b * 4 + g) * 128) * 2048;

  const int kmj = tid >> 4;
  const int kmc = ((tid & 15) ^ (kmj & 7)) * 8;
  const bf16_t* Ksrc = Kp + (size_t)kmj * 128 + kmc;
  const int vd = tid >> 2, vc = tid & 3;
  const bf16_t* Vsrc = Vp + (size_t)vd * 2048 + vc * 8;
  const int vdst = vd * VROW + (vc & 1) * 16 + (vc >> 1) * 4;

  auto loadK = [&](int j0, uint4& ka, uint4& kb) {
    const bf16_t* s = Ksrc + (size_t)j0 * 128;
    ka = *reinterpret_cast<const uint4*>(s);
    kb = *reinterpret_cast<const uint4*>(s + 16 * 128);
  };
  auto writeK = [&](int bufi, uint4 ka, uint4 kb) {
    *reinterpret_cast<uint4*>(Ks + bufi * 4096 + tid * 8) = ka;
    *reinterpret_cast<uint4*>(Ks + bufi * 4096 + 2048 + tid * 8) = kb;
  };
  auto loadV = [&](int j0, uint4& a, uint4& bqv) {
    a = *reinterpret_cast<const uint4*>(Vsrc + j0);
    bqv = *reinterpret_cast<const uint4*>(Vsrc + 64 * 2048 + j0);
  };
  auto writeV = [&](int bufi, uint4 a, uint4 bqv) {
    bf16_t* p = Vs + bufi * 128 * VROW + vdst;
    *reinterpret_cast<uint2*>(p) = make_uint2(a.x, a.y);
    *reinterpret_cast<uint2*>(p + 8) = make_uint2(a.z, a.w);
    bf16_t* p1 = p + 64 * VROW;
    *reinterpret_cast<uint2*>(p1) = make_uint2(bqv.x, bqv.y);
    *reinterpret_cast<uint2*>(p1 + 8) = make_uint2(bqv.z, bqv.w);
  };

  const int kxor = (lr & 7) << 4;

  for (int sidx = 0; sidx < nseg; ++sidx) {
    const int i0b = ((sidx == 0) ? sx0 : sx1) * 64;
    const int i0 = i0b + w * 16;
    const int qrow = i0 + lr;

    bf16x8 qf[4];
#pragma unroll
    for (int kc = 0; kc < 4; ++kc)
      qf[kc] = *reinterpret_cast<const bf16x8*>(&Qp[(size_t)qrow * 128 + kc * 32 + lc * 8]);

    f32x4 o[8] = {};
    float mrun = -1e30f, lrun = 0.f;  // lrun LANE-PARTIAL (reduced at epilogue)

    int lo = i0b - 1023;
    if (lo < 0) lo = 0;
    const int jstart = lo & ~31;
    const int jlast = i0b + 32;

    {
      uint4 ka, kb, va, vb;
      loadK(jstart, ka, kb);
      loadV(jstart, va, vb);
      writeK(0, ka, kb);
      writeV(0, va, vb);
    }
    __syncthreads();

    int buf = 0;
    for (int j0 = jstart; j0 <= jlast; j0 += 32) {
      const int nxt = j0 + 32;
      uint4 ka, kb, va, vb;
      const bool do_stage = (nxt <= jlast);
      if (do_stage) {
        loadK(nxt, ka, kb);
        loadV(nxt, va, vb);
      }

      const bool active = (j0 <= i0 + 15) && (j0 + 31 > i0 - 1024);
      if (active) {
        const bf16_t* Kb = Ks + buf * 4096;
        const bf16_t* Vb = Vs + buf * 128 * VROW;
        f32x4 s0 = {}, s1 = {};
        __builtin_amdgcn_s_setprio(1);
#pragma unroll
        for (int kc = 0; kc < 4; ++kc) {
          int col = ((kc * 64 + lc * 16) ^ kxor) >> 1;
          bf16x8 kf0 = *reinterpret_cast<const bf16x8*>(Kb + lr * 128 + col);
          bf16x8 kf1 = *reinterpret_cast<const bf16x8*>(Kb + (16 + lr) * 128 + col);
          s0 = __builtin_amdgcn_mfma_f32_16x16x32_bf16(kf0, qf[kc], s0, 0, 0, 0);
          s1 = __builtin_amdgcn_mfma_f32_16x16x32_bf16(kf1, qf[kc], s1, 0, 0, 0);
        }
        __builtin_amdgcn_s_setprio(0);
        bf16x8 vvf[8];
#pragma unroll
        for (int f = 0; f < 8; ++f)
          vvf[f] = *reinterpret_cast<const bf16x8*>(Vb + (f * 16 + lr) * VROW + lc * 8);

        const bool full = (j0 + 31 <= i0) && (j0 >= i0 - 1008);
        if (!full) {
#pragma unroll
          for (int r = 0; r < 4; ++r) {
            int ja = j0 + lc * 4 + r;
            int jb = ja + 16;
            bool oka = (ja <= qrow) && (ja > qrow - 1024);
            bool okb = (jb <= qrow) && (jb > qrow - 1024);
            s0[r] = oka ? s0[r] : -1e30f;
            s1[r] = okb ? s1[r] : -1e30f;
          }
        }
        float rm = fmaxf(fmaxf(fmaxf(s0[0], s0[1]), fmaxf(s0[2], s0[3])),
                         fmaxf(fmaxf(s1[0], s1[1]), fmaxf(s1[2], s1[3])));

        if (!__all(rm <= mrun + 11.5f)) {
          rm = fmaxf(rm, __shfl_xor(rm, 16));
          rm = fmaxf(rm, __shfl_xor(rm, 32));
          float mnew = fmaxf(mrun, rm);
          float alpha = exp2f(mrun - mnew);
          mrun = mnew;
          lrun *= alpha;
#pragma unroll
          for (int f = 0; f < 8; ++f)
#pragma unroll
            for (int r = 0; r < 4; ++r) o[f][r] *= alpha;
        }

        float p0[4], p1[4], ps = 0.f;
#pragma unroll
        for (int r = 0; r < 4; ++r) {
          p0[r] = exp2f(s0[r] - mrun);
          p1[r] = exp2f(s1[r] - mrun);
          ps += p0[r] + p1[r];
        }
        lrun += ps;

        bf16_t pb[8];
#pragma unroll
        for (int r = 0; r < 4; ++r) {
          pb[r] = __float2bfloat16(p0[r]);
          pb[r + 4] = __float2bfloat16(p1[r]);
        }
        bf16x8 pfrag = *reinterpret_cast<bf16x8*>(pb);

        __builtin_amdgcn_s_setprio(1);
#pragma unroll
        for (int f = 0; f < 8; ++f)
          o[f] = __builtin_amdgcn_mfma_f32_16x16x32_bf16(vvf[f], pfrag, o[f], 0, 0, 0);
        __builtin_amdgcn_s_setprio(0);
      }

      if (do_stage) {
        writeK(buf ^ 1, ka, kb);
        writeV(buf ^ 1, va, vb);
      }
      __syncthreads();
      buf ^= 1;
    }

    float lt = lrun;
    lt += __shfl_xor(lt, 16);
    lt += __shfl_xor(lt, 32);
    float inv = 1.f / lt;
#pragma unroll
    for (int f = 0; f < 8; ++f) {
      bf16_t ob[4];
#pragma unroll
      for (int r = 0; r < 4; ++r) ob[r] = __float2bfloat16(o[f][r] * inv);
      *reinterpret_cast<uint2*>(
          &Y[((size_t)(b * 2048 + qrow)) * 2048 + h * 128 + f * 16 + lc * 4]) =
          *reinterpret_cast<uint2*>(ob);
    }
  }
}

// ---------------- launch ----------------
extern "C" void kernel_launch(void* const* d_in, const int* in_sizes, int n_in,
                              void* d_out, int out_size, void* d_ws, size_t ws_size,
                              hipStream_t stream) {
  const float* x = (const float*)d_in[0];
  const float* cosp = (const float*)d_in[1];
  const float* sinp = (const float*)d_in[2];
  const float* Wa = (const float*)d_in[3];
  const float* Wp = (const float*)d_in[4];
  float* out = (float*)d_out;

  bf16_t* ws = (bf16_t*)d_ws;
  bf16_t* xb = ws;                  // x bf16 -> reused as Q
  bf16_t* wab = ws + 8388608;       // W_attn bf16 -> reused as K,V
  bf16_t* wpb = ws + 14680064;      // W_proj bf16
  bf16_t* qkv = ws + 18874368;      // qkv bf16 -> reused as Y,Vt
  bf16_t* Q = xb;                   // [B][H][T][HS]
  bf16_t* Kr = wab;                 // [B][G][T][HS]
  bf16_t* V = wab + 2097152;        // [B][G][T][HS]
  bf16_t* Y = qkv;                  // [B][T][H][HS]
  bf16_t* Vt = qkv + 8388608;       // [B][G][HS][T]

  cvt_f32_to_bf16<<<4096, 256, 0, stream>>>(x, xb, 1048576);
  cvt_f32_to_bf16<<<3072, 256, 0, stream>>>(Wa, wab, 786432);
  cvt_f32_to_bf16<<<2048, 256, 0, stream>>>(Wp, wpb, 524288);

  // qkv = xb @ wab^T : M=4096 N=3072 K=2048  (BN=192 -> 16x16 = 256 blocks)
  gemm256<192, bf16_t><<<dim3(16, 16), 512, 0, stream>>>(xb, wab, qkv, 4096, 3072, 2048);

  rope_scatter<<<4096, 256, 0, stream>>>(qkv, cosp, sinp, Q, Kr, V);

  transpose_v<<<dim3(64, 4, 8), dim3(32, 8), 0, stream>>>(V, Vt);

  attn_swa<<<dim3(24, 16, 2), 256, 0, stream>>>(Q, Kr, Vt, Y);

  // out = Y @ wpb^T : M=4096 N=2048 K=2048  (BN=128 -> 16x16 = 256 blocks)
  gemm256<128, float><<<dim3(16, 16), 512, 0, stream>>>(Y, wpb, out, 4096, 2048, 2048);
}